// Round 6
// baseline (96.928 us; speedup 1.0000x reference)
//
#include <hip/hip_runtime.h>
#include <hip/hip_bf16.h>
#include <stdint.h>

#define BB 8
#define TT 2048
#define CC 768
#define NTPB 288   // flash tasks per batch: sum_{qt=0..63} ceil((qt+1)/8)

typedef __bf16 bf16x8 __attribute__((ext_vector_type(8)));
typedef float f32x4 __attribute__((ext_vector_type(4)));
typedef float f32x16 __attribute__((ext_vector_type(16)));

__device__ inline __bf16 f2b(float f) {
    __hip_bfloat16 h = __float2bfloat16(f);
    return __builtin_bit_cast(__bf16, h);
}
__device__ inline ushort f2bits(float f) {
    __hip_bfloat16 h = __float2bfloat16(f);
    return __builtin_bit_cast(ushort, h);
}
__device__ inline uint32_t cvtpk(float lo, float hi) {
    uint32_t r;
    asm("v_cvt_pk_bf16_f32 %0, %1, %2" : "=v"(r) : "v"(lo), "v"(hi));
    return r;
}
__device__ inline void pswap(uint32_t& a, uint32_t& b) {
    asm volatile("v_permlane32_swap_b32 %0, %1" : "+v"(a), "+v"(b));
}
__device__ inline bf16x8 cvt8(float4 a, float4 b) {
    bf16x8 r;
    r[0] = f2b(a.x); r[1] = f2b(a.y); r[2] = f2b(a.z); r[3] = f2b(a.w);
    r[4] = f2b(b.x); r[5] = f2b(b.y); r[6] = f2b(b.z); r[7] = f2b(b.w);
    return r;
}

// ---------------- Kernel 0: W transpose to bf16 [3][64][768] -------------
__launch_bounds__(256)
__global__ void wt_kernel(const float* __restrict__ Wk, const float* __restrict__ Wq,
                          const float* __restrict__ Wv, ushort* __restrict__ Wt) {
    __shared__ float tile[64][65];
    int m  = blockIdx.x / 12;
    int c0 = (blockIdx.x % 12) * 64;
    const float* W = (m == 0) ? Wq : ((m == 1) ? Wk : Wv);
    int tid = threadIdx.x;
#pragma unroll
    for (int i = 0; i < 4; i++) {
        int r   = (tid >> 4) + i * 16;
        int col = (tid & 15) * 4;
        float4 v = *(const float4*)&W[(size_t)(c0 + r) * 64 + col];
        tile[r][col] = v.x; tile[r][col + 1] = v.y;
        tile[r][col + 2] = v.z; tile[r][col + 3] = v.w;
    }
    __syncthreads();
    int j  = tid >> 2;
    int cc = (tid & 3) * 16;
    ushort tmp[16];
#pragma unroll
    for (int e = 0; e < 16; e++) tmp[e] = f2bits(tile[cc + e][j]);
    ushort* dst = &Wt[(size_t)(m * 64 + j) * CC + c0 + cc];
    *(uint4*)(dst)     = *(uint4*)&tmp[0];
    *(uint4*)(dst + 8) = *(uint4*)&tmp[8];
}

// ---------------- Kernel 1: QKV GEMM, barrier-free 16x192 waves ----------
// 1024 independent waves (grid 256 x 4 waves). Full-unroll K loop with
// distance-2 register prefetch of A (x rows, HBM) and 12 B frags (Wt, L2).
// q output pre-scaled by 0.125.
__launch_bounds__(256, 1)
__global__ void qkv_kernel(const float* __restrict__ x, const ushort* __restrict__ Wt,
                           ushort* __restrict__ qws, ushort* __restrict__ kws,
                           ushort* __restrict__ vws) {
    int tid  = threadIdx.x;
    int wid  = tid >> 6;
    int lane = tid & 63;
    int l15  = lane & 15;
    int hi4  = lane >> 4;
    int row0 = (blockIdx.x * 4 + wid) * 16;

    const float*  xp = x  + (size_t)(row0 + l15) * CC + hi4 * 8;
    const ushort* wb = Wt + (size_t)l15 * CC + hi4 * 8;

    f32x4 acc[12];
#pragma unroll
    for (int nt = 0; nt < 12; nt++) acc[nt] = (f32x4){0.f, 0.f, 0.f, 0.f};

    float4 a0[3], a1[3];
    uint4  bb[3][12];

    auto lda = [&](int s, int t) {
        const float* p = xp + t * 32;
        a0[s] = *(const float4*)(p);
        a1[s] = *(const float4*)(p + 4);
    };
    auto ldb = [&](int s, int t) {
#pragma unroll
        for (int nt = 0; nt < 12; nt++)
            bb[s][nt] = *(const uint4*)(wb + (size_t)nt * 16 * CC + t * 32);
    };

    lda(0, 0); ldb(0, 0);
    lda(1, 1); ldb(1, 1);
#pragma unroll
    for (int t = 0; t < 24; t++) {
        int cs = t % 3;
        int ns = (t + 2) % 3;
        if (t < 22) { lda(ns, t + 2); ldb(ns, t + 2); }
        bf16x8 af = cvt8(a0[cs], a1[cs]);
#pragma unroll
        for (int nt = 0; nt < 12; nt++)
            acc[nt] = __builtin_amdgcn_mfma_f32_16x16x32_bf16(
                af, __builtin_bit_cast(bf16x8, bb[cs][nt]), acc[nt], 0, 0, 0);
    }

    int r0   = row0 + 4 * hi4;
    int bidx = row0 >> 11;
    int t0   = r0 & 2047;
#pragma unroll
    for (int nt = 0; nt < 12; nt++) {
        int m    = nt >> 2;
        int jcol = (nt & 3) * 16 + l15;
        if (m == 0) {
#pragma unroll
            for (int r = 0; r < 4; r++)
                qws[(size_t)(r0 + r) * 64 + jcol] = f2bits(acc[nt][r] * 0.125f);
        } else if (m == 1) {
#pragma unroll
            for (int r = 0; r < 4; r++)
                kws[(size_t)(r0 + r) * 64 + jcol] = f2bits(acc[nt][r]);
        } else {
            ushort4 pk;
            pk.x = f2bits(acc[nt][0]);
            pk.y = f2bits(acc[nt][1]);
            pk.z = f2bits(acc[nt][2]);
            pk.w = f2bits(acc[nt][3]);
            *(ushort4*)&vws[((size_t)bidx * 64 + jcol) * TT + t0] = pk;
        }
    }
}

// ---------------- Kernel 2: flash attention, 32x32 swapped, no LDS -------
// Wave-task = (b, 32-row q-tile, 256-row KV segment). S^T = mfma(K,Q) puts a
// full P-row per lane; softmax in-register (lane pair l,l+32 share q-row);
// P->bf16 frags via v_cvt_pk_bf16_f32 + v_permlane32_swap; O^T = mfma(V^T,P^T).
__launch_bounds__(256, 2)
__global__ void flash_kernel(const ushort* __restrict__ qg, const ushort* __restrict__ kg,
                             const ushort* __restrict__ vtg, float* __restrict__ out,
                             float* __restrict__ pO, float* __restrict__ pM,
                             float* __restrict__ pL) {
    int lane = threadIdx.x & 63;
    int wid  = threadIdx.x >> 6;
    int l31  = lane & 31;
    int hi   = lane >> 5;

    int gw = blockIdx.x * 4 + wid;
    int b  = gw / NTPB;
    int tp = gw - b * NTPB;
    int j  = 0;
    while (tp >= 4 * (j + 1) * (j + 2)) j++;     // wave-uniform
    int r_    = tp - 4 * j * (j + 1);
    int qt    = 8 * j + r_ / (j + 1);
    int seg   = r_ - (qt - 8 * j) * (j + 1);
    int nseg  = j + 1;
    int Q0    = qt * 32;
    int s_beg = seg * 256;
    int s_end = (s_beg + 256 < Q0 + 32) ? s_beg + 256 : Q0 + 32;

    // Q fragments (B operand), q = Q0 + l31, h = c*16 + hi*8 + [0..7]
    const ushort* qp = qg + ((size_t)b * TT + Q0 + l31) * 64 + hi * 8;
    bf16x8 qf[4];
#pragma unroll
    for (int c = 0; c < 4; c++)
        qf[c] = __builtin_bit_cast(bf16x8, *(const uint4*)(qp + c * 16));

    f32x16 o0 = (f32x16)(0.f), o1 = (f32x16)(0.f);
    float m  = -INFINITY;
    float lp = 0.f;

    for (int s0 = s_beg; s0 < s_end; s0 += 64) {
        // K frags (A operand): kv = s0 + t*32 + l31
        bf16x8 kf[2][4];
#pragma unroll
        for (int t = 0; t < 2; t++) {
            const ushort* kp = kg + ((size_t)b * TT + s0 + t * 32 + l31) * 64 + hi * 8;
#pragma unroll
            for (int c = 0; c < 4; c++)
                kf[t][c] = __builtin_bit_cast(bf16x8, *(const uint4*)(kp + c * 16));
        }
        // V frags (A operand of PV): h = ht*32 + l31, kv = s0 + c*16 + hi*8
        bf16x8 vf[2][4];
#pragma unroll
        for (int ht = 0; ht < 2; ht++) {
            const ushort* vp = vtg + ((size_t)b * 64 + ht * 32 + l31) * TT + s0 + hi * 8;
#pragma unroll
            for (int c = 0; c < 4; c++)
                vf[ht][c] = __builtin_bit_cast(bf16x8, *(const uint4*)(vp + c * 16));
        }

        f32x16 st0 = (f32x16)(0.f), st1 = (f32x16)(0.f);
        __builtin_amdgcn_s_setprio(1);
#pragma unroll
        for (int c = 0; c < 4; c++)
            st0 = __builtin_amdgcn_mfma_f32_32x32x16_bf16(kf[0][c], qf[c], st0, 0, 0, 0);
#pragma unroll
        for (int c = 0; c < 4; c++)
            st1 = __builtin_amdgcn_mfma_f32_32x32x16_bf16(kf[1][c], qf[c], st1, 0, 0, 0);
        __builtin_amdgcn_s_setprio(0);

        // causal mask: reg r -> kv_local = (r&3)+8*(r>>2)+4*hi (+32 for tile1)
        if (s0 + 63 > Q0) {
            int th0 = Q0 + l31 - s0 - 4 * hi;
            int th1 = th0 - 32;
#pragma unroll
            for (int r = 0; r < 16; r++) {
                int kvl = (r & 3) + 8 * (r >> 2);
                if (kvl > th0) st0[r] = -INFINITY;
                if (kvl > th1) st1[r] = -INFINITY;
            }
        }

        // in-register softmax; lanes l and l^32 hold the two halves of one q-row
        float lmax = -INFINITY;
#pragma unroll
        for (int r = 0; r < 16; r++) lmax = fmaxf(lmax, fmaxf(st0[r], st1[r]));
        float pmax = fmaxf(lmax, __shfl_xor(lmax, 32));
        if (__any(pmax > m + 8.f)) {
            float mn = fmaxf(m, pmax);
            float al = __expf(m - mn);
            lp *= al;
#pragma unroll
            for (int r = 0; r < 16; r++) { o0[r] *= al; o1[r] *= al; }
            m = mn;
        }
#pragma unroll
        for (int r = 0; r < 16; r++) {
            st0[r] = __expf(st0[r] - m); lp += st0[r];
            st1[r] = __expf(st1[r] - m); lp += st1[r];
        }

        // P -> bf16 A/B-fragments: 4 cvt_pk + 2 permlane_swap per chunk
        bf16x8 pf[4];
        {
            uint32_t w0, w1, w2, w3;
            w0 = cvtpk(st0[0], st0[1]);  w1 = cvtpk(st0[2], st0[3]);
            w2 = cvtpk(st0[4], st0[5]);  w3 = cvtpk(st0[6], st0[7]);
            pswap(w0, w2); pswap(w1, w3);
            uint4 u0 = {w0, w1, w2, w3}; pf[0] = __builtin_bit_cast(bf16x8, u0);
            w0 = cvtpk(st0[8], st0[9]);  w1 = cvtpk(st0[10], st0[11]);
            w2 = cvtpk(st0[12], st0[13]); w3 = cvtpk(st0[14], st0[15]);
            pswap(w0, w2); pswap(w1, w3);
            uint4 u1 = {w0, w1, w2, w3}; pf[1] = __builtin_bit_cast(bf16x8, u1);
            w0 = cvtpk(st1[0], st1[1]);  w1 = cvtpk(st1[2], st1[3]);
            w2 = cvtpk(st1[4], st1[5]);  w3 = cvtpk(st1[6], st1[7]);
            pswap(w0, w2); pswap(w1, w3);
            uint4 u2 = {w0, w1, w2, w3}; pf[2] = __builtin_bit_cast(bf16x8, u2);
            w0 = cvtpk(st1[8], st1[9]);  w1 = cvtpk(st1[10], st1[11]);
            w2 = cvtpk(st1[12], st1[13]); w3 = cvtpk(st1[14], st1[15]);
            pswap(w0, w2); pswap(w1, w3);
            uint4 u3 = {w0, w1, w2, w3}; pf[3] = __builtin_bit_cast(bf16x8, u3);
        }

        __builtin_amdgcn_s_setprio(1);
#pragma unroll
        for (int c = 0; c < 4; c++)
            o0 = __builtin_amdgcn_mfma_f32_32x32x16_bf16(vf[0][c], pf[c], o0, 0, 0, 0);
#pragma unroll
        for (int c = 0; c < 4; c++)
            o1 = __builtin_amdgcn_mfma_f32_32x32x16_bf16(vf[1][c], pf[c], o1, 0, 0, 0);
        __builtin_amdgcn_s_setprio(0);
    }

    float lsum = lp + __shfl_xor(lp, 32);

    // O^T regs: col q = l31; reg r of tile ht -> h = (r&3)+8*(r>>2)+4*hi+32*ht
    if (nseg == 1) {
        float inv = 1.f / lsum;
        float* ob = out + ((size_t)b * TT + Q0 + l31) * 64;
#pragma unroll
        for (int g = 0; g < 4; g++) {
            float4 v0 = {o0[4*g] * inv, o0[4*g+1] * inv, o0[4*g+2] * inv, o0[4*g+3] * inv};
            *(float4*)(ob + 8 * g + 4 * hi) = v0;
            float4 v1 = {o1[4*g] * inv, o1[4*g+1] * inv, o1[4*g+2] * inv, o1[4*g+3] * inv};
            *(float4*)(ob + 32 + 8 * g + 4 * hi) = v1;
        }
    } else {
        int   tb = b * NTPB + tp;
        float* pb = pO + (size_t)tb * 2048 + (size_t)l31 * 64;
#pragma unroll
        for (int g = 0; g < 4; g++) {
            float4 v0 = {o0[4*g], o0[4*g+1], o0[4*g+2], o0[4*g+3]};
            *(float4*)(pb + 8 * g + 4 * hi) = v0;
            float4 v1 = {o1[4*g], o1[4*g+1], o1[4*g+2], o1[4*g+3]};
            *(float4*)(pb + 32 + 8 * g + 4 * hi) = v1;
        }
        if (hi == 0) {
            pM[(size_t)tb * 32 + l31] = m;
            pL[(size_t)tb * 32 + l31] = lsum;
        }
    }
}

// ---------------- Kernel 3: merge partials (qt >= 8) ---------------------
__launch_bounds__(256)
__global__ void merge_kernel(const float* __restrict__ pO, const float* __restrict__ pM,
                             const float* __restrict__ pL, float* __restrict__ out) {
    int b    = blockIdx.x / 56;
    int qt   = 8 + (blockIdx.x % 56);
    int j    = qt >> 3;
    int nseg = j + 1;
    int tbase = b * NTPB + 4 * j * (j + 1) + (qt - 8 * j) * (j + 1);

    int qrow = threadIdx.x >> 3;
    int h0   = (threadIdx.x & 7) * 8;

    float mstar = -INFINITY;
    for (int s = 0; s < nseg; s++)
        mstar = fmaxf(mstar, pM[(size_t)(tbase + s) * 32 + qrow]);

    float oa[8] = {0.f, 0.f, 0.f, 0.f, 0.f, 0.f, 0.f, 0.f};
    float la = 0.f;
    for (int s = 0; s < nseg; s++) {
        float w = __expf(pM[(size_t)(tbase + s) * 32 + qrow] - mstar);
        la += w * pL[(size_t)(tbase + s) * 32 + qrow];
        const float* pp = pO + (size_t)(tbase + s) * 2048 + (size_t)qrow * 64 + h0;
        float4 v0 = *(const float4*)(pp);
        float4 v1 = *(const float4*)(pp + 4);
        oa[0] += w * v0.x; oa[1] += w * v0.y; oa[2] += w * v0.z; oa[3] += w * v0.w;
        oa[4] += w * v1.x; oa[5] += w * v1.y; oa[6] += w * v1.z; oa[7] += w * v1.w;
    }
    float inv = 1.f / la;
    float* ob = out + ((size_t)b * TT + qt * 32 + qrow) * 64 + h0;
    float4 r0 = {oa[0] * inv, oa[1] * inv, oa[2] * inv, oa[3] * inv};
    float4 r1 = {oa[4] * inv, oa[5] * inv, oa[6] * inv, oa[7] * inv};
    *(float4*)(ob)     = r0;
    *(float4*)(ob + 4) = r1;
}

// ---------------- launch --------------------------------------------------
extern "C" void kernel_launch(void* const* d_in, const int* in_sizes, int n_in,
                              void* d_out, int out_size, void* d_ws, size_t ws_size,
                              hipStream_t stream) {
    const float* x  = (const float*)d_in[0];
    const float* Wk = (const float*)d_in[1];
    const float* Wq = (const float*)d_in[2];
    const float* Wv = (const float*)d_in[3];
    float* out = (float*)d_out;

    char* ws = (char*)d_ws;
    ushort* Wt  = (ushort*)(ws);                 // 288 KB
    ushort* qws = (ushort*)(ws + 0x50000);       // 2 MB
    ushort* kws = (ushort*)(ws + 0x250000);      // 2 MB
    ushort* vws = (ushort*)(ws + 0x450000);      // 2 MB  [b][h][t]
    float*  pO  = (float*)(ws + 0x650000);       // 2304*2048*4 = 18.9 MB
    float*  pM  = (float*)(ws + 0x1850000);      // 2304*32*4 = 288 KB
    float*  pL  = (float*)(ws + 0x1898000);      // 288 KB

    wt_kernel<<<36, 256, 0, stream>>>(Wk, Wq, Wv, Wt);
    qkv_kernel<<<(BB * TT) / 64, 256, 0, stream>>>(x, Wt, qws, kws, vws);
    flash_kernel<<<(BB * NTPB) / 4, 256, 0, stream>>>(qws, kws, vws, out, pO, pM, pL);
    merge_kernel<<<BB * 56, 256, 0, stream>>>(pO, pM, pL, out);
}

// Round 7
// 67.520 us; speedup vs baseline: 1.4355x; 1.4355x over previous
//
#include <hip/hip_runtime.h>
#include <hip/hip_bf16.h>
#include <stdint.h>

#define BB 8
#define TT 2048
#define CC 768
#define NTPB 288   // flash tasks per batch: sum_{qt=0..63} ceil((qt+1)/8)

typedef __bf16 bf16x8 __attribute__((ext_vector_type(8)));
typedef float f32x4 __attribute__((ext_vector_type(4)));
typedef float f32x16 __attribute__((ext_vector_type(16)));

__device__ inline __bf16 f2b(float f) {
    __hip_bfloat16 h = __float2bfloat16(f);
    return __builtin_bit_cast(__bf16, h);
}
__device__ inline ushort f2bits(float f) {
    __hip_bfloat16 h = __float2bfloat16(f);
    return __builtin_bit_cast(ushort, h);
}
__device__ inline uint32_t cvtpk(float lo, float hi) {
    uint32_t r;
    asm("v_cvt_pk_bf16_f32 %0, %1, %2" : "=v"(r) : "v"(lo), "v"(hi));
    return r;
}
__device__ inline void pswap(uint32_t& a, uint32_t& b) {
    asm volatile("v_permlane32_swap_b32 %0, %1" : "+v"(a), "+v"(b));
}

#define GLL16(gp, lp)                                                          \
    __builtin_amdgcn_global_load_lds(                                          \
        (const __attribute__((address_space(1))) unsigned int*)(gp),           \
        (__attribute__((address_space(3))) unsigned int*)(lp), 16, 0, 0)

// ---------------- Kernel 0: W transpose to bf16 [3][64][768] -------------
__launch_bounds__(256)
__global__ void wt_kernel(const float* __restrict__ Wk, const float* __restrict__ Wq,
                          const float* __restrict__ Wv, ushort* __restrict__ Wt) {
    __shared__ float tile[64][65];
    int m  = blockIdx.x / 12;
    int c0 = (blockIdx.x % 12) * 64;
    const float* W = (m == 0) ? Wq : ((m == 1) ? Wk : Wv);
    int tid = threadIdx.x;
#pragma unroll
    for (int i = 0; i < 4; i++) {
        int r   = (tid >> 4) + i * 16;
        int col = (tid & 15) * 4;
        float4 v = *(const float4*)&W[(size_t)(c0 + r) * 64 + col];
        tile[r][col] = v.x; tile[r][col + 1] = v.y;
        tile[r][col + 2] = v.z; tile[r][col + 3] = v.w;
    }
    __syncthreads();
    int j  = tid >> 2;
    int cc = (tid & 3) * 16;
    ushort tmp[16];
#pragma unroll
    for (int e = 0; e < 16; e++) tmp[e] = f2bits(tile[cc + e][j]);
    ushort* dst = &Wt[(size_t)(m * 64 + j) * CC + c0 + cc];
    *(uint4*)(dst)     = *(uint4*)&tmp[0];
    *(uint4*)(dst + 8) = *(uint4*)&tmp[8];
}

// ---------------- Kernel 1: QKV GEMM, global_load_lds 4-deep pipeline ----
// Block: 32 rows x 192 cols, 4 waves (wave w: cols [w*48,+48), all 32 rows).
// BK=64 -> 12 tiles; tiles t..t+3 in flight (counted vmcnt, never drained).
// LDS x-tile fp32 linear (DMA dest), source pre-swizzled chunk^=(row&7);
// reads apply the same XOR -> conflict-free. q pre-scaled by 0.125.
__launch_bounds__(256, 2)
__global__ void qkv_kernel(const float* __restrict__ x, const ushort* __restrict__ Wt,
                           ushort* __restrict__ qws, ushort* __restrict__ kws,
                           ushort* __restrict__ vws) {
    __shared__ float xs[4][32 * 64];   // 4 buffers x 8 KB

    int tid  = threadIdx.x;
    int wid  = tid >> 6;
    int lane = tid & 63;
    int l15  = lane & 15;
    int hi4  = lane >> 4;
    int row0 = blockIdx.x * 32;

    // staging: thread owns LDS chunks tid and tid+256 (16 B each, linear).
    // LDS chunk (row, cc) holds global chunk gc = cc ^ (row&7).
    int ch0 = tid,        r0s = ch0 >> 4, gc0 = (ch0 & 15) ^ (r0s & 7);
    int ch1 = tid + 256,  r1s = ch1 >> 4, gc1 = (ch1 & 15) ^ (r1s & 7);
    const float* gp0 = x + (size_t)(row0 + r0s) * CC + gc0 * 4;
    const float* gp1 = x + (size_t)(row0 + r1s) * CC + gc1 * 4;

    const ushort* wtp[3];
#pragma unroll
    for (int nt = 0; nt < 3; nt++)
        wtp[nt] = Wt + (size_t)(wid * 48 + nt * 16 + l15) * CC + hi4 * 8;

    f32x4 acc[2][3];
#pragma unroll
    for (int mm = 0; mm < 2; mm++)
#pragma unroll
        for (int nt = 0; nt < 3; nt++) acc[mm][nt] = (f32x4){0.f, 0.f, 0.f, 0.f};

    auto stage = [&](int t) {
        int buf = t & 3;
        GLL16(gp0 + t * 64, &xs[buf][ch0 * 4]);
        GLL16(gp1 + t * 64, &xs[buf][ch1 * 4]);
    };

    stage(0); stage(1); stage(2); stage(3);   // 8 loads in flight

#pragma unroll
    for (int t = 0; t < 12; t++) {
        if (t < 9)       asm volatile("s_waitcnt vmcnt(6)" ::: "memory");
        else if (t == 9) asm volatile("s_waitcnt vmcnt(4)" ::: "memory");
        else if (t == 10) asm volatile("s_waitcnt vmcnt(2)" ::: "memory");
        else             asm volatile("s_waitcnt vmcnt(0)" ::: "memory");
        __builtin_amdgcn_s_barrier();
        __builtin_amdgcn_sched_barrier(0);

        int buf = t & 3;
        int kb  = t * 64;
#pragma unroll
        for (int ks = 0; ks < 2; ks++) {
            bf16x8 af[2];
#pragma unroll
            for (int mm = 0; mm < 2; mm++) {
                int row = mm * 16 + l15;
                int g   = ks * 8 + hi4 * 2;
                const float* base = &xs[buf][row * 64];
                float4 fa = *(const float4*)(base + (((g)     ^ (row & 7)) * 4));
                float4 fb = *(const float4*)(base + (((g + 1) ^ (row & 7)) * 4));
                uint32_t w0 = cvtpk(fa.x, fa.y), w1 = cvtpk(fa.z, fa.w);
                uint32_t w2 = cvtpk(fb.x, fb.y), w3 = cvtpk(fb.z, fb.w);
                uint4 u = {w0, w1, w2, w3};
                af[mm] = __builtin_bit_cast(bf16x8, u);
            }
#pragma unroll
            for (int nt = 0; nt < 3; nt++) {
                bf16x8 b = __builtin_bit_cast(bf16x8, *(const uint4*)(wtp[nt] + kb + ks * 32));
                acc[0][nt] = __builtin_amdgcn_mfma_f32_16x16x32_bf16(af[0], b, acc[0][nt], 0, 0, 0);
                acc[1][nt] = __builtin_amdgcn_mfma_f32_16x16x32_bf16(af[1], b, acc[1][nt], 0, 0, 0);
            }
        }
        __builtin_amdgcn_s_barrier();      // all reads of buf done
        if (t + 4 < 12) stage(t + 4);      // refill; loads cross barriers
    }

    // epilogue: q (x0.125), k row-major bf16; v transposed [b][h][t]
    int bidx = row0 >> 11;
#pragma unroll
    for (int mm = 0; mm < 2; mm++) {
        int r0 = row0 + mm * 16 + 4 * hi4;
        int t0 = r0 & 2047;
#pragma unroll
        for (int nt = 0; nt < 3; nt++) {
            int c = wid * 48 + nt * 16 + l15;
            int m = c >> 6;
            int j = c & 63;
            if (m == 0) {
#pragma unroll
                for (int r = 0; r < 4; r++)
                    qws[(size_t)(r0 + r) * 64 + j] = f2bits(acc[mm][nt][r] * 0.125f);
            } else if (m == 1) {
#pragma unroll
                for (int r = 0; r < 4; r++)
                    kws[(size_t)(r0 + r) * 64 + j] = f2bits(acc[mm][nt][r]);
            } else {
                ushort4 pk;
                pk.x = f2bits(acc[mm][nt][0]);
                pk.y = f2bits(acc[mm][nt][1]);
                pk.z = f2bits(acc[mm][nt][2]);
                pk.w = f2bits(acc[mm][nt][3]);
                *(ushort4*)&vws[((size_t)bidx * 64 + j) * TT + t0] = pk;
            }
        }
    }
}

// ---------------- Kernel 2: flash attention, 32x32 swapped, no LDS -------
__launch_bounds__(256, 2)
__global__ void flash_kernel(const ushort* __restrict__ qg, const ushort* __restrict__ kg,
                             const ushort* __restrict__ vtg, float* __restrict__ out,
                             float* __restrict__ pO, float* __restrict__ pM,
                             float* __restrict__ pL) {
    int lane = threadIdx.x & 63;
    int wid  = threadIdx.x >> 6;
    int l31  = lane & 31;
    int hi   = lane >> 5;

    int gw = blockIdx.x * 4 + wid;
    int b  = gw / NTPB;
    int tp = gw - b * NTPB;
    int j  = 0;
    while (tp >= 4 * (j + 1) * (j + 2)) j++;     // wave-uniform
    int r_    = tp - 4 * j * (j + 1);
    int qt    = 8 * j + r_ / (j + 1);
    int seg   = r_ - (qt - 8 * j) * (j + 1);
    int nseg  = j + 1;
    int Q0    = qt * 32;
    int s_beg = seg * 256;
    int s_end = (s_beg + 256 < Q0 + 32) ? s_beg + 256 : Q0 + 32;

    const ushort* qp = qg + ((size_t)b * TT + Q0 + l31) * 64 + hi * 8;
    bf16x8 qf[4];
#pragma unroll
    for (int c = 0; c < 4; c++)
        qf[c] = __builtin_bit_cast(bf16x8, *(const uint4*)(qp + c * 16));

    f32x16 o0 = (f32x16)(0.f), o1 = (f32x16)(0.f);
    float m  = -INFINITY;
    float lp = 0.f;

    for (int s0 = s_beg; s0 < s_end; s0 += 64) {
        bf16x8 kf[2][4];
#pragma unroll
        for (int t = 0; t < 2; t++) {
            const ushort* kp = kg + ((size_t)b * TT + s0 + t * 32 + l31) * 64 + hi * 8;
#pragma unroll
            for (int c = 0; c < 4; c++)
                kf[t][c] = __builtin_bit_cast(bf16x8, *(const uint4*)(kp + c * 16));
        }
        bf16x8 vf[2][4];
#pragma unroll
        for (int ht = 0; ht < 2; ht++) {
            const ushort* vp = vtg + ((size_t)b * 64 + ht * 32 + l31) * TT + s0 + hi * 8;
#pragma unroll
            for (int c = 0; c < 4; c++)
                vf[ht][c] = __builtin_bit_cast(bf16x8, *(const uint4*)(vp + c * 16));
        }

        f32x16 st0 = (f32x16)(0.f), st1 = (f32x16)(0.f);
        __builtin_amdgcn_s_setprio(1);
#pragma unroll
        for (int c = 0; c < 4; c++)
            st0 = __builtin_amdgcn_mfma_f32_32x32x16_bf16(kf[0][c], qf[c], st0, 0, 0, 0);
#pragma unroll
        for (int c = 0; c < 4; c++)
            st1 = __builtin_amdgcn_mfma_f32_32x32x16_bf16(kf[1][c], qf[c], st1, 0, 0, 0);
        __builtin_amdgcn_s_setprio(0);

        if (s0 + 63 > Q0) {
            int th0 = Q0 + l31 - s0 - 4 * hi;
            int th1 = th0 - 32;
#pragma unroll
            for (int r = 0; r < 16; r++) {
                int kvl = (r & 3) + 8 * (r >> 2);
                if (kvl > th0) st0[r] = -INFINITY;
                if (kvl > th1) st1[r] = -INFINITY;
            }
        }

        float lmax = -INFINITY;
#pragma unroll
        for (int r = 0; r < 16; r++) lmax = fmaxf(lmax, fmaxf(st0[r], st1[r]));
        float pmax = fmaxf(lmax, __shfl_xor(lmax, 32));
        if (__any(pmax > m + 8.f)) {
            float mn = fmaxf(m, pmax);
            float al = __expf(m - mn);
            lp *= al;
#pragma unroll
            for (int r = 0; r < 16; r++) { o0[r] *= al; o1[r] *= al; }
            m = mn;
        }
#pragma unroll
        for (int r = 0; r < 16; r++) {
            st0[r] = __expf(st0[r] - m); lp += st0[r];
            st1[r] = __expf(st1[r] - m); lp += st1[r];
        }

        bf16x8 pf[4];
        {
            uint32_t w0, w1, w2, w3;
            w0 = cvtpk(st0[0], st0[1]);  w1 = cvtpk(st0[2], st0[3]);
            w2 = cvtpk(st0[4], st0[5]);  w3 = cvtpk(st0[6], st0[7]);
            pswap(w0, w2); pswap(w1, w3);
            uint4 u0 = {w0, w1, w2, w3}; pf[0] = __builtin_bit_cast(bf16x8, u0);
            w0 = cvtpk(st0[8], st0[9]);  w1 = cvtpk(st0[10], st0[11]);
            w2 = cvtpk(st0[12], st0[13]); w3 = cvtpk(st0[14], st0[15]);
            pswap(w0, w2); pswap(w1, w3);
            uint4 u1 = {w0, w1, w2, w3}; pf[1] = __builtin_bit_cast(bf16x8, u1);
            w0 = cvtpk(st1[0], st1[1]);  w1 = cvtpk(st1[2], st1[3]);
            w2 = cvtpk(st1[4], st1[5]);  w3 = cvtpk(st1[6], st1[7]);
            pswap(w0, w2); pswap(w1, w3);
            uint4 u2 = {w0, w1, w2, w3}; pf[2] = __builtin_bit_cast(bf16x8, u2);
            w0 = cvtpk(st1[8], st1[9]);  w1 = cvtpk(st1[10], st1[11]);
            w2 = cvtpk(st1[12], st1[13]); w3 = cvtpk(st1[14], st1[15]);
            pswap(w0, w2); pswap(w1, w3);
            uint4 u3 = {w0, w1, w2, w3}; pf[3] = __builtin_bit_cast(bf16x8, u3);
        }

        __builtin_amdgcn_s_setprio(1);
#pragma unroll
        for (int c = 0; c < 4; c++)
            o0 = __builtin_amdgcn_mfma_f32_32x32x16_bf16(vf[0][c], pf[c], o0, 0, 0, 0);
#pragma unroll
        for (int c = 0; c < 4; c++)
            o1 = __builtin_amdgcn_mfma_f32_32x32x16_bf16(vf[1][c], pf[c], o1, 0, 0, 0);
        __builtin_amdgcn_s_setprio(0);
    }

    float lsum = lp + __shfl_xor(lp, 32);

    if (nseg == 1) {
        float inv = 1.f / lsum;
        float* ob = out + ((size_t)b * TT + Q0 + l31) * 64;
#pragma unroll
        for (int g = 0; g < 4; g++) {
            float4 v0 = {o0[4*g] * inv, o0[4*g+1] * inv, o0[4*g+2] * inv, o0[4*g+3] * inv};
            *(float4*)(ob + 8 * g + 4 * hi) = v0;
            float4 v1 = {o1[4*g] * inv, o1[4*g+1] * inv, o1[4*g+2] * inv, o1[4*g+3] * inv};
            *(float4*)(ob + 32 + 8 * g + 4 * hi) = v1;
        }
    } else {
        int   tb = b * NTPB + tp;
        float* pb = pO + (size_t)tb * 2048 + (size_t)l31 * 64;
#pragma unroll
        for (int g = 0; g < 4; g++) {
            float4 v0 = {o0[4*g], o0[4*g+1], o0[4*g+2], o0[4*g+3]};
            *(float4*)(pb + 8 * g + 4 * hi) = v0;
            float4 v1 = {o1[4*g], o1[4*g+1], o1[4*g+2], o1[4*g+3]};
            *(float4*)(pb + 32 + 8 * g + 4 * hi) = v1;
        }
        if (hi == 0) {
            pM[(size_t)tb * 32 + l31] = m;
            pL[(size_t)tb * 32 + l31] = lsum;
        }
    }
}

// ---------------- Kernel 3: merge partials (qt >= 8) ---------------------
__launch_bounds__(256)
__global__ void merge_kernel(const float* __restrict__ pO, const float* __restrict__ pM,
                             const float* __restrict__ pL, float* __restrict__ out) {
    int b    = blockIdx.x / 56;
    int qt   = 8 + (blockIdx.x % 56);
    int j    = qt >> 3;
    int nseg = j + 1;
    int tbase = b * NTPB + 4 * j * (j + 1) + (qt - 8 * j) * (j + 1);

    int qrow = threadIdx.x >> 3;
    int h0   = (threadIdx.x & 7) * 8;

    float mstar = -INFINITY;
    for (int s = 0; s < nseg; s++)
        mstar = fmaxf(mstar, pM[(size_t)(tbase + s) * 32 + qrow]);

    float oa[8] = {0.f, 0.f, 0.f, 0.f, 0.f, 0.f, 0.f, 0.f};
    float la = 0.f;
    for (int s = 0; s < nseg; s++) {
        float w = __expf(pM[(size_t)(tbase + s) * 32 + qrow] - mstar);
        la += w * pL[(size_t)(tbase + s) * 32 + qrow];
        const float* pp = pO + (size_t)(tbase + s) * 2048 + (size_t)qrow * 64 + h0;
        float4 v0 = *(const float4*)(pp);
        float4 v1 = *(const float4*)(pp + 4);
        oa[0] += w * v0.x; oa[1] += w * v0.y; oa[2] += w * v0.z; oa[3] += w * v0.w;
        oa[4] += w * v1.x; oa[5] += w * v1.y; oa[6] += w * v1.z; oa[7] += w * v1.w;
    }
    float inv = 1.f / la;
    float* ob = out + ((size_t)b * TT + qt * 32 + qrow) * 64 + h0;
    float4 r0 = {oa[0] * inv, oa[1] * inv, oa[2] * inv, oa[3] * inv};
    float4 r1 = {oa[4] * inv, oa[5] * inv, oa[6] * inv, oa[7] * inv};
    *(float4*)(ob)     = r0;
    *(float4*)(ob + 4) = r1;
}

// ---------------- launch --------------------------------------------------
extern "C" void kernel_launch(void* const* d_in, const int* in_sizes, int n_in,
                              void* d_out, int out_size, void* d_ws, size_t ws_size,
                              hipStream_t stream) {
    const float* x  = (const float*)d_in[0];
    const float* Wk = (const float*)d_in[1];
    const float* Wq = (const float*)d_in[2];
    const float* Wv = (const float*)d_in[3];
    float* out = (float*)d_out;

    char* ws = (char*)d_ws;
    ushort* Wt  = (ushort*)(ws);                 // 288 KB
    ushort* qws = (ushort*)(ws + 0x50000);       // 2 MB
    ushort* kws = (ushort*)(ws + 0x250000);      // 2 MB
    ushort* vws = (ushort*)(ws + 0x450000);      // 2 MB  [b][h][t]
    float*  pO  = (float*)(ws + 0x650000);       // 18.9 MB
    float*  pM  = (float*)(ws + 0x1850000);      // 288 KB
    float*  pL  = (float*)(ws + 0x1898000);      // 288 KB

    wt_kernel<<<36, 256, 0, stream>>>(Wk, Wq, Wv, Wt);
    qkv_kernel<<<(BB * TT) / 32, 256, 0, stream>>>(x, Wt, qws, kws, vws);
    flash_kernel<<<(BB * NTPB) / 4, 256, 0, stream>>>(qws, kws, vws, out, pO, pM, pL);
    merge_kernel<<<BB * 56, 256, 0, stream>>>(pO, pM, pL, out);
}

// Round 8
// 62.877 us; speedup vs baseline: 1.5416x; 1.0738x over previous
//
#include <hip/hip_runtime.h>
#include <hip/hip_bf16.h>
#include <stdint.h>

#define BB 8
#define TT 2048
#define CC 768
#define NTPB 72   // flash block-tasks per batch: sum_{g=0..15} ceil((g+1)/2)

typedef __bf16 bf16x8 __attribute__((ext_vector_type(8)));
typedef float f32x4 __attribute__((ext_vector_type(4)));
typedef float f32x16 __attribute__((ext_vector_type(16)));

__device__ inline __bf16 f2b(float f) {
    __hip_bfloat16 h = __float2bfloat16(f);
    return __builtin_bit_cast(__bf16, h);
}
__device__ inline ushort f2bits(float f) {
    __hip_bfloat16 h = __float2bfloat16(f);
    return __builtin_bit_cast(ushort, h);
}
__device__ inline uint32_t cvtpk(float lo, float hi) {
    uint32_t r;
    asm("v_cvt_pk_bf16_f32 %0, %1, %2" : "=v"(r) : "v"(lo), "v"(hi));
    return r;
}
__device__ inline void pswap(uint32_t& a, uint32_t& b) {
    asm volatile("v_permlane32_swap_b32 %0, %1" : "+v"(a), "+v"(b));
}

#define GLL16(gp, lp)                                                          \
    __builtin_amdgcn_global_load_lds(                                          \
        (const __attribute__((address_space(1))) unsigned int*)(gp),           \
        (__attribute__((address_space(3))) unsigned int*)(lp), 16, 0, 0)

// ---------------- Kernel 0: W transpose to bf16 [3][64][768] -------------
__launch_bounds__(256)
__global__ void wt_kernel(const float* __restrict__ Wk, const float* __restrict__ Wq,
                          const float* __restrict__ Wv, ushort* __restrict__ Wt) {
    __shared__ float tile[64][65];
    int m  = blockIdx.x / 12;
    int c0 = (blockIdx.x % 12) * 64;
    const float* W = (m == 0) ? Wq : ((m == 1) ? Wk : Wv);
    int tid = threadIdx.x;
#pragma unroll
    for (int i = 0; i < 4; i++) {
        int r   = (tid >> 4) + i * 16;
        int col = (tid & 15) * 4;
        float4 v = *(const float4*)&W[(size_t)(c0 + r) * 64 + col];
        tile[r][col] = v.x; tile[r][col + 1] = v.y;
        tile[r][col + 2] = v.z; tile[r][col + 3] = v.w;
    }
    __syncthreads();
    int j  = tid >> 2;
    int cc = (tid & 3) * 16;
    ushort tmp[16];
#pragma unroll
    for (int e = 0; e < 16; e++) tmp[e] = f2bits(tile[cc + e][j]);
    ushort* dst = &Wt[(size_t)(m * 64 + j) * CC + c0 + cc];
    *(uint4*)(dst)     = *(uint4*)&tmp[0];
    *(uint4*)(dst + 8) = *(uint4*)&tmp[8];
}

// ---------------- Kernel 1: QKV GEMM (unchanged from R7) -----------------
__launch_bounds__(256, 2)
__global__ void qkv_kernel(const float* __restrict__ x, const ushort* __restrict__ Wt,
                           ushort* __restrict__ qws, ushort* __restrict__ kws,
                           ushort* __restrict__ vws) {
    __shared__ float xs[4][32 * 64];   // 4 buffers x 8 KB

    int tid  = threadIdx.x;
    int wid  = tid >> 6;
    int lane = tid & 63;
    int l15  = lane & 15;
    int hi4  = lane >> 4;
    int row0 = blockIdx.x * 32;

    int ch0 = tid,        r0s = ch0 >> 4, gc0 = (ch0 & 15) ^ (r0s & 7);
    int ch1 = tid + 256,  r1s = ch1 >> 4, gc1 = (ch1 & 15) ^ (r1s & 7);
    const float* gp0 = x + (size_t)(row0 + r0s) * CC + gc0 * 4;
    const float* gp1 = x + (size_t)(row0 + r1s) * CC + gc1 * 4;

    const ushort* wtp[3];
#pragma unroll
    for (int nt = 0; nt < 3; nt++)
        wtp[nt] = Wt + (size_t)(wid * 48 + nt * 16 + l15) * CC + hi4 * 8;

    f32x4 acc[2][3];
#pragma unroll
    for (int mm = 0; mm < 2; mm++)
#pragma unroll
        for (int nt = 0; nt < 3; nt++) acc[mm][nt] = (f32x4){0.f, 0.f, 0.f, 0.f};

    auto stage = [&](int t) {
        int buf = t & 3;
        GLL16(gp0 + t * 64, &xs[buf][ch0 * 4]);
        GLL16(gp1 + t * 64, &xs[buf][ch1 * 4]);
    };

    stage(0); stage(1); stage(2); stage(3);

#pragma unroll
    for (int t = 0; t < 12; t++) {
        if (t < 9)       asm volatile("s_waitcnt vmcnt(6)" ::: "memory");
        else if (t == 9) asm volatile("s_waitcnt vmcnt(4)" ::: "memory");
        else if (t == 10) asm volatile("s_waitcnt vmcnt(2)" ::: "memory");
        else             asm volatile("s_waitcnt vmcnt(0)" ::: "memory");
        __builtin_amdgcn_s_barrier();
        __builtin_amdgcn_sched_barrier(0);

        int buf = t & 3;
        int kb  = t * 64;
#pragma unroll
        for (int ks = 0; ks < 2; ks++) {
            bf16x8 af[2];
#pragma unroll
            for (int mm = 0; mm < 2; mm++) {
                int row = mm * 16 + l15;
                int g   = ks * 8 + hi4 * 2;
                const float* base = &xs[buf][row * 64];
                float4 fa = *(const float4*)(base + (((g)     ^ (row & 7)) * 4));
                float4 fb = *(const float4*)(base + (((g + 1) ^ (row & 7)) * 4));
                uint32_t w0 = cvtpk(fa.x, fa.y), w1 = cvtpk(fa.z, fa.w);
                uint32_t w2 = cvtpk(fb.x, fb.y), w3 = cvtpk(fb.z, fb.w);
                uint4 u = {w0, w1, w2, w3};
                af[mm] = __builtin_bit_cast(bf16x8, u);
            }
#pragma unroll
            for (int nt = 0; nt < 3; nt++) {
                bf16x8 b = __builtin_bit_cast(bf16x8, *(const uint4*)(wtp[nt] + kb + ks * 32));
                acc[0][nt] = __builtin_amdgcn_mfma_f32_16x16x32_bf16(af[0], b, acc[0][nt], 0, 0, 0);
                acc[1][nt] = __builtin_amdgcn_mfma_f32_16x16x32_bf16(af[1], b, acc[1][nt], 0, 0, 0);
            }
        }
        __builtin_amdgcn_s_barrier();
        if (t + 4 < 12) stage(t + 4);
    }

    int bidx = row0 >> 11;
#pragma unroll
    for (int mm = 0; mm < 2; mm++) {
        int r0 = row0 + mm * 16 + 4 * hi4;
        int t0 = r0 & 2047;
#pragma unroll
        for (int nt = 0; nt < 3; nt++) {
            int c = wid * 48 + nt * 16 + l15;
            int m = c >> 6;
            int j = c & 63;
            if (m == 0) {
#pragma unroll
                for (int r = 0; r < 4; r++)
                    qws[(size_t)(r0 + r) * 64 + j] = f2bits(acc[mm][nt][r] * 0.125f);
            } else if (m == 1) {
#pragma unroll
                for (int r = 0; r < 4; r++)
                    kws[(size_t)(r0 + r) * 64 + j] = f2bits(acc[mm][nt][r]);
            } else {
                ushort4 pk;
                pk.x = f2bits(acc[mm][nt][0]);
                pk.y = f2bits(acc[mm][nt][1]);
                pk.z = f2bits(acc[mm][nt][2]);
                pk.w = f2bits(acc[mm][nt][3]);
                *(ushort4*)&vws[((size_t)bidx * 64 + j) * TT + t0] = pk;
            }
        }
    }
}

// ---------------- Kernel 2: flash attention, LDS-shared K/V --------------
// Block-task = (b, 128-q-row block g, 256-kv segment). 4 waves x 32 q-rows
// share K/V tiles staged in LDS via global_load_lds (3-deep, counted vmcnt).
// In-register swapped softmax (S^T=mfma(K,Q)), O^T=mfma(V^T,P^T).
__launch_bounds__(256, 3)
__global__ void flash_kernel(const ushort* __restrict__ qg, const ushort* __restrict__ kg,
                             const ushort* __restrict__ vtg, float* __restrict__ out,
                             float* __restrict__ pO, float* __restrict__ pM,
                             float* __restrict__ pL) {
    __shared__ ushort Ks[3][64 * 64];   // K tile [kv][h], swizzled chunks
    __shared__ ushort Vs[3][64 * 64];   // V^T tile [h][kv], swizzled chunks

    int tid  = threadIdx.x;
    int wid  = tid >> 6;
    int lane = tid & 63;
    int l31  = lane & 31;
    int hi   = lane >> 5;

    int b  = blockIdx.x / NTPB;
    int tp = blockIdx.x - b * NTPB;
    int g  = 0;
    while (tp >= ((g + 2) * (g + 2)) >> 2) g++;         // block-uniform
    int seg   = tp - (((g + 1) * (g + 1)) >> 2);
    int nseg  = (g + 2) >> 1;
    int Qb    = g * 128;
    int Q0w   = Qb + wid * 32;
    int s_beg = seg * 256;
    int s_end = (s_beg + 256 < Qb + 128) ? s_beg + 256 : Qb + 128;
    int nt    = (s_end - s_beg) >> 6;

    // staging geometry: thread covers 16B chunks tid and tid+256 of each tile.
    // LDS chunk (row r, cc) holds global chunk gc = cc ^ (r&7); rows +32 same.
    int rS  = tid >> 3;
    int gcS = (tid & 7) ^ (rS & 7);
    const ushort* kS = kg  + ((size_t)b * TT + rS) * 64 + gcS * 8;
    const ushort* vS = vtg + ((size_t)b * 64 + rS) * TT + gcS * 8;

    auto stage = [&](int tt) {
        int buf = tt % 3;
        int ss  = s_beg + tt * 64;
        const ushort* kA = kS + (size_t)ss * 64;
        const ushort* vA = vS + ss;
        GLL16(kA,            &Ks[buf][tid * 8]);
        GLL16(kA + 32 * 64,  &Ks[buf][(tid + 256) * 8]);
        GLL16(vA,            &Vs[buf][tid * 8]);
        GLL16(vA + 32 * TT,  &Vs[buf][(tid + 256) * 8]);
    };

    // Q fragments (B operand): q = Q0w + l31, h = c*16 + hi*8 + [0..7]
    const ushort* qp = qg + ((size_t)b * TT + Q0w + l31) * 64 + hi * 8;
    bf16x8 qf[4];
#pragma unroll
    for (int c = 0; c < 4; c++)
        qf[c] = __builtin_bit_cast(bf16x8, *(const uint4*)(qp + c * 16));

    f32x16 o0 = (f32x16)(0.f), o1 = (f32x16)(0.f);
    float m  = -INFINITY;
    float lp = 0.f;

    stage(0);
    if (nt > 1) stage(1);

    for (int t = 0; t < nt; t++) {
        if (t < nt - 1) asm volatile("s_waitcnt vmcnt(4)" ::: "memory");
        else            asm volatile("s_waitcnt vmcnt(0)" ::: "memory");
        __builtin_amdgcn_s_barrier();
        __builtin_amdgcn_sched_barrier(0);
        if (t + 2 < nt) stage(t + 2);

        int s0 = s_beg + t * 64;
        if (s0 < Q0w + 32) {
            int buf = t % 3;
            // K frags from LDS: kv row rk = tt*32 + l31, chunk (c*2+hi)^(rk&7)
            bf16x8 kf[2][4];
#pragma unroll
            for (int tt = 0; tt < 2; tt++) {
                int rk = tt * 32 + l31;
                const ushort* base = &Ks[buf][rk * 64];
                int sw = rk & 7;
#pragma unroll
                for (int c = 0; c < 4; c++)
                    kf[tt][c] = __builtin_bit_cast(bf16x8,
                        *(const uint4*)(base + (((c * 2 + hi) ^ sw) * 8)));
            }

            f32x16 st0 = (f32x16)(0.f), st1 = (f32x16)(0.f);
            __builtin_amdgcn_s_setprio(1);
#pragma unroll
            for (int c = 0; c < 4; c++)
                st0 = __builtin_amdgcn_mfma_f32_32x32x16_bf16(kf[0][c], qf[c], st0, 0, 0, 0);
#pragma unroll
            for (int c = 0; c < 4; c++)
                st1 = __builtin_amdgcn_mfma_f32_32x32x16_bf16(kf[1][c], qf[c], st1, 0, 0, 0);
            __builtin_amdgcn_s_setprio(0);

            if (s0 + 63 > Q0w) {
                int th0 = Q0w + l31 - s0 - 4 * hi;
                int th1 = th0 - 32;
#pragma unroll
                for (int r = 0; r < 16; r++) {
                    int kvl = (r & 3) + 8 * (r >> 2);
                    if (kvl > th0) st0[r] = -INFINITY;
                    if (kvl > th1) st1[r] = -INFINITY;
                }
            }

            float lmax = -INFINITY;
#pragma unroll
            for (int r = 0; r < 16; r++) lmax = fmaxf(lmax, fmaxf(st0[r], st1[r]));
            float pmax = fmaxf(lmax, __shfl_xor(lmax, 32));
            if (__any(pmax > m + 8.f)) {
                float mn = fmaxf(m, pmax);
                float al = __expf(m - mn);
                lp *= al;
#pragma unroll
                for (int r = 0; r < 16; r++) { o0[r] *= al; o1[r] *= al; }
                m = mn;
            }
#pragma unroll
            for (int r = 0; r < 16; r++) {
                st0[r] = __expf(st0[r] - m); lp += st0[r];
                st1[r] = __expf(st1[r] - m); lp += st1[r];
            }

            bf16x8 pf[4];
            {
                uint32_t w0, w1, w2, w3;
                w0 = cvtpk(st0[0], st0[1]);  w1 = cvtpk(st0[2], st0[3]);
                w2 = cvtpk(st0[4], st0[5]);  w3 = cvtpk(st0[6], st0[7]);
                pswap(w0, w2); pswap(w1, w3);
                uint4 u0 = {w0, w1, w2, w3}; pf[0] = __builtin_bit_cast(bf16x8, u0);
                w0 = cvtpk(st0[8], st0[9]);  w1 = cvtpk(st0[10], st0[11]);
                w2 = cvtpk(st0[12], st0[13]); w3 = cvtpk(st0[14], st0[15]);
                pswap(w0, w2); pswap(w1, w3);
                uint4 u1 = {w0, w1, w2, w3}; pf[1] = __builtin_bit_cast(bf16x8, u1);
                w0 = cvtpk(st1[0], st1[1]);  w1 = cvtpk(st1[2], st1[3]);
                w2 = cvtpk(st1[4], st1[5]);  w3 = cvtpk(st1[6], st1[7]);
                pswap(w0, w2); pswap(w1, w3);
                uint4 u2 = {w0, w1, w2, w3}; pf[2] = __builtin_bit_cast(bf16x8, u2);
                w0 = cvtpk(st1[8], st1[9]);  w1 = cvtpk(st1[10], st1[11]);
                w2 = cvtpk(st1[12], st1[13]); w3 = cvtpk(st1[14], st1[15]);
                pswap(w0, w2); pswap(w1, w3);
                uint4 u3 = {w0, w1, w2, w3}; pf[3] = __builtin_bit_cast(bf16x8, u3);
            }

            // V frags from LDS: h row rv = ht*32 + l31, chunk (c*2+hi)^(rv&7)
            bf16x8 vf[2][4];
#pragma unroll
            for (int ht = 0; ht < 2; ht++) {
                int rv = ht * 32 + l31;
                const ushort* base = &Vs[buf][rv * 64];
                int sw = rv & 7;
#pragma unroll
                for (int c = 0; c < 4; c++)
                    vf[ht][c] = __builtin_bit_cast(bf16x8,
                        *(const uint4*)(base + (((c * 2 + hi) ^ sw) * 8)));
            }

            __builtin_amdgcn_s_setprio(1);
#pragma unroll
            for (int c = 0; c < 4; c++)
                o0 = __builtin_amdgcn_mfma_f32_32x32x16_bf16(vf[0][c], pf[c], o0, 0, 0, 0);
#pragma unroll
            for (int c = 0; c < 4; c++)
                o1 = __builtin_amdgcn_mfma_f32_32x32x16_bf16(vf[1][c], pf[c], o1, 0, 0, 0);
            __builtin_amdgcn_s_setprio(0);
        }
    }

    float lsum = lp + __shfl_xor(lp, 32);

    if (nseg == 1) {
        float inv = 1.f / lsum;
        float* ob = out + ((size_t)b * TT + Q0w + l31) * 64;
#pragma unroll
        for (int gg = 0; gg < 4; gg++) {
            float4 v0 = {o0[4*gg] * inv, o0[4*gg+1] * inv, o0[4*gg+2] * inv, o0[4*gg+3] * inv};
            *(float4*)(ob + 8 * gg + 4 * hi) = v0;
            float4 v1 = {o1[4*gg] * inv, o1[4*gg+1] * inv, o1[4*gg+2] * inv, o1[4*gg+3] * inv};
            *(float4*)(ob + 32 + 8 * gg + 4 * hi) = v1;
        }
    } else {
        int tb = b * NTPB + tp;
        float* pb = pO + (size_t)tb * 8192 + (size_t)(wid * 32 + l31) * 64;
#pragma unroll
        for (int gg = 0; gg < 4; gg++) {
            float4 v0 = {o0[4*gg], o0[4*gg+1], o0[4*gg+2], o0[4*gg+3]};
            *(float4*)(pb + 8 * gg + 4 * hi) = v0;
            float4 v1 = {o1[4*gg], o1[4*gg+1], o1[4*gg+2], o1[4*gg+3]};
            *(float4*)(pb + 32 + 8 * gg + 4 * hi) = v1;
        }
        if (hi == 0) {
            pM[(size_t)tb * 128 + wid * 32 + l31] = m;
            pL[(size_t)tb * 128 + wid * 32 + l31] = lsum;
        }
    }
}

// ---------------- Kernel 3: merge partials (g >= 2) ----------------------
__launch_bounds__(256)
__global__ void merge_kernel(const float* __restrict__ pO, const float* __restrict__ pM,
                             const float* __restrict__ pL, float* __restrict__ out) {
    int b    = blockIdx.x / 14;
    int g    = 2 + (blockIdx.x % 14);
    int nseg = (g + 2) >> 1;
    int tbase = b * NTPB + (((g + 1) * (g + 1)) >> 2);

    int row = threadIdx.x >> 1;          // 0..127
    int hh  = (threadIdx.x & 1) * 32;

    float mstar = -INFINITY;
    for (int s = 0; s < nseg; s++)
        mstar = fmaxf(mstar, pM[(size_t)(tbase + s) * 128 + row]);

    float oa[32];
#pragma unroll
    for (int i = 0; i < 32; i++) oa[i] = 0.f;
    float la = 0.f;
    for (int s = 0; s < nseg; s++) {
        float w = __expf(pM[(size_t)(tbase + s) * 128 + row] - mstar);
        la += w * pL[(size_t)(tbase + s) * 128 + row];
        const float* pp = pO + (size_t)(tbase + s) * 8192 + (size_t)row * 64 + hh;
#pragma unroll
        for (int i = 0; i < 8; i++) {
            float4 v = *(const float4*)(pp + i * 4);
            oa[i*4]   += w * v.x; oa[i*4+1] += w * v.y;
            oa[i*4+2] += w * v.z; oa[i*4+3] += w * v.w;
        }
    }
    float inv = 1.f / la;
    float* ob = out + ((size_t)b * TT + g * 128 + row) * 64 + hh;
#pragma unroll
    for (int i = 0; i < 8; i++) {
        float4 v = {oa[i*4] * inv, oa[i*4+1] * inv, oa[i*4+2] * inv, oa[i*4+3] * inv};
        *(float4*)(ob + i * 4) = v;
    }
}

// ---------------- launch --------------------------------------------------
extern "C" void kernel_launch(void* const* d_in, const int* in_sizes, int n_in,
                              void* d_out, int out_size, void* d_ws, size_t ws_size,
                              hipStream_t stream) {
    const float* x  = (const float*)d_in[0];
    const float* Wk = (const float*)d_in[1];
    const float* Wq = (const float*)d_in[2];
    const float* Wv = (const float*)d_in[3];
    float* out = (float*)d_out;

    char* ws = (char*)d_ws;
    ushort* Wt  = (ushort*)(ws);                 // 288 KB
    ushort* qws = (ushort*)(ws + 0x50000);       // 2 MB
    ushort* kws = (ushort*)(ws + 0x250000);      // 2 MB
    ushort* vws = (ushort*)(ws + 0x450000);      // 2 MB  [b][h][t]
    float*  pO  = (float*)(ws + 0x650000);       // 576*8192*4 = 18.9 MB
    float*  pM  = (float*)(ws + 0x1850000);      // 576*128*4 = 288 KB
    float*  pL  = (float*)(ws + 0x1898000);      // 288 KB

    wt_kernel<<<36, 256, 0, stream>>>(Wk, Wq, Wv, Wt);
    qkv_kernel<<<(BB * TT) / 32, 256, 0, stream>>>(x, Wt, qws, kws, vws);
    flash_kernel<<<BB * NTPB, 256, 0, stream>>>(qws, kws, vws, out, pO, pM, pL);
    merge_kernel<<<BB * 14, 256, 0, stream>>>(pO, pM, pL, out);
}

// Round 9
// 57.254 us; speedup vs baseline: 1.6930x; 1.0982x over previous
//
#include <hip/hip_runtime.h>
#include <hip/hip_bf16.h>
#include <stdint.h>

#define BB 8
#define TT 2048
#define CC 768
#define NTPB 72   // flash block-tasks per batch: sum_{g=0..15} ceil((g+1)/2)

typedef __bf16 bf16x8 __attribute__((ext_vector_type(8)));
typedef float f32x4 __attribute__((ext_vector_type(4)));
typedef float f32x16 __attribute__((ext_vector_type(16)));

__device__ inline __bf16 f2b(float f) {
    __hip_bfloat16 h = __float2bfloat16(f);
    return __builtin_bit_cast(__bf16, h);
}
__device__ inline ushort f2bits(float f) {
    __hip_bfloat16 h = __float2bfloat16(f);
    return __builtin_bit_cast(ushort, h);
}
__device__ inline uint32_t cvtpk(float lo, float hi) {
    uint32_t r;
    asm("v_cvt_pk_bf16_f32 %0, %1, %2" : "=v"(r) : "v"(lo), "v"(hi));
    return r;
}
__device__ inline void pswap(uint32_t& a, uint32_t& b) {
    asm volatile("v_permlane32_swap_b32 %0, %1" : "+v"(a), "+v"(b));
}

#define GLL16(gp, lp)                                                          \
    __builtin_amdgcn_global_load_lds(                                          \
        (const __attribute__((address_space(1))) unsigned int*)(gp),           \
        (__attribute__((address_space(3))) unsigned int*)(lp), 16, 0, 0)

// ---------------- Kernel 0: W -> fragment-major bf16 WtF -----------------
// WtF element (c, k), c = m*64+j in [0,192), k in [0,768):
//   flat = ((k>>5)*192 + c)*32 + ((k>>3)&3)*8 + (k&7)
// One wave B-load (fixed kc, c = c0+l15, hi4 = lane>>4) covers contiguous 1KB.
__launch_bounds__(256)
__global__ void wt_kernel(const float* __restrict__ Wk, const float* __restrict__ Wq,
                          const float* __restrict__ Wv, ushort* __restrict__ WtF) {
    __shared__ float tile[64][65];
    int m  = blockIdx.x / 12;
    int c0 = (blockIdx.x % 12) * 64;     // k-range base
    const float* W = (m == 0) ? Wq : ((m == 1) ? Wk : Wv);
    int tid = threadIdx.x;
#pragma unroll
    for (int i = 0; i < 4; i++) {
        int r   = (tid >> 4) + i * 16;
        int col = (tid & 15) * 4;
        float4 v = *(const float4*)&W[(size_t)(c0 + r) * 64 + col];
        tile[r][col] = v.x; tile[r][col + 1] = v.y;
        tile[r][col + 2] = v.z; tile[r][col + 3] = v.w;
    }
    __syncthreads();
    int j  = tid >> 2;            // col within 64
    int cc = (tid & 3) * 16;      // k offset within this 64-k block
    ushort tmp[16];
#pragma unroll
    for (int e = 0; e < 16; e++) tmp[e] = f2bits(tile[cc + e][j]);
    int c  = m * 64 + j;
    int kb = c0 + cc;             // multiple of 16
    int kc = kb >> 5;
    int h4 = (kb >> 3) & 3;       // 0 or 2
    ushort* dst = &WtF[((size_t)kc * 192 + c) * 32 + h4 * 8];
    *(uint4*)(dst)     = *(uint4*)&tmp[0];
    *(uint4*)(dst + 8) = *(uint4*)&tmp[8];
}

// ---------------- Kernel 1: QKV GEMM, gll pipeline + coalesced WtF -------
// Block: 32 rows x 192 cols, 4 waves. BK=64 -> 12 tiles, 4-deep LDS pipeline
// with counted vmcnt (loads cross barriers, never drain mid-loop).
// B loads now contiguous 1KB per wave from WtF. q pre-scaled by 0.125.
__launch_bounds__(256, 2)
__global__ void qkv_kernel(const float* __restrict__ x, const ushort* __restrict__ WtF,
                           ushort* __restrict__ qws, ushort* __restrict__ kws,
                           ushort* __restrict__ vws) {
    __shared__ float xs[4][32 * 64];   // 4 buffers x 8 KB

    int tid  = threadIdx.x;
    int wid  = tid >> 6;
    int lane = tid & 63;
    int l15  = lane & 15;
    int hi4  = lane >> 4;
    int row0 = blockIdx.x * 32;

    int ch0 = tid,        r0s = ch0 >> 4, gc0 = (ch0 & 15) ^ (r0s & 7);
    int ch1 = tid + 256,  r1s = ch1 >> 4, gc1 = (ch1 & 15) ^ (r1s & 7);
    const float* gp0 = x + (size_t)(row0 + r0s) * CC + gc0 * 4;
    const float* gp1 = x + (size_t)(row0 + r1s) * CC + gc1 * 4;

    // fragment-major B pointers: contiguous 1KB per wave-load
    const ushort* wtp[3];
#pragma unroll
    for (int nt = 0; nt < 3; nt++)
        wtp[nt] = WtF + ((size_t)(wid * 48 + nt * 16 + l15) * 4 + hi4) * 8;

    f32x4 acc[2][3];
#pragma unroll
    for (int mm = 0; mm < 2; mm++)
#pragma unroll
        for (int nt = 0; nt < 3; nt++) acc[mm][nt] = (f32x4){0.f, 0.f, 0.f, 0.f};

    auto stage = [&](int t) {
        int buf = t & 3;
        GLL16(gp0 + t * 64, &xs[buf][ch0 * 4]);
        GLL16(gp1 + t * 64, &xs[buf][ch1 * 4]);
    };

    stage(0); stage(1); stage(2); stage(3);

#pragma unroll
    for (int t = 0; t < 12; t++) {
        if (t < 9)       asm volatile("s_waitcnt vmcnt(6)" ::: "memory");
        else if (t == 9) asm volatile("s_waitcnt vmcnt(4)" ::: "memory");
        else if (t == 10) asm volatile("s_waitcnt vmcnt(2)" ::: "memory");
        else             asm volatile("s_waitcnt vmcnt(0)" ::: "memory");
        __builtin_amdgcn_s_barrier();
        __builtin_amdgcn_sched_barrier(0);

        int buf = t & 3;
#pragma unroll
        for (int ks = 0; ks < 2; ks++) {
            int kc = 2 * t + ks;
            bf16x8 af[2];
#pragma unroll
            for (int mm = 0; mm < 2; mm++) {
                int row = mm * 16 + l15;
                int g   = ks * 8 + hi4 * 2;
                const float* base = &xs[buf][row * 64];
                float4 fa = *(const float4*)(base + (((g)     ^ (row & 7)) * 4));
                float4 fb = *(const float4*)(base + (((g + 1) ^ (row & 7)) * 4));
                uint32_t w0 = cvtpk(fa.x, fa.y), w1 = cvtpk(fa.z, fa.w);
                uint32_t w2 = cvtpk(fb.x, fb.y), w3 = cvtpk(fb.z, fb.w);
                uint4 u = {w0, w1, w2, w3};
                af[mm] = __builtin_bit_cast(bf16x8, u);
            }
#pragma unroll
            for (int nt = 0; nt < 3; nt++) {
                bf16x8 b = __builtin_bit_cast(bf16x8,
                    *(const uint4*)(wtp[nt] + (size_t)kc * 6144));
                acc[0][nt] = __builtin_amdgcn_mfma_f32_16x16x32_bf16(af[0], b, acc[0][nt], 0, 0, 0);
                acc[1][nt] = __builtin_amdgcn_mfma_f32_16x16x32_bf16(af[1], b, acc[1][nt], 0, 0, 0);
            }
        }
        __builtin_amdgcn_s_barrier();
        if (t + 4 < 12) stage(t + 4);
    }

    int bidx = row0 >> 11;
#pragma unroll
    for (int mm = 0; mm < 2; mm++) {
        int r0 = row0 + mm * 16 + 4 * hi4;
        int t0 = r0 & 2047;
#pragma unroll
        for (int nt = 0; nt < 3; nt++) {
            int c = wid * 48 + nt * 16 + l15;
            int m = c >> 6;
            int j = c & 63;
            if (m == 0) {
#pragma unroll
                for (int r = 0; r < 4; r++)
                    qws[(size_t)(r0 + r) * 64 + j] = f2bits(acc[mm][nt][r] * 0.125f);
            } else if (m == 1) {
#pragma unroll
                for (int r = 0; r < 4; r++)
                    kws[(size_t)(r0 + r) * 64 + j] = f2bits(acc[mm][nt][r]);
            } else {
                ushort4 pk;
                pk.x = f2bits(acc[mm][nt][0]);
                pk.y = f2bits(acc[mm][nt][1]);
                pk.z = f2bits(acc[mm][nt][2]);
                pk.w = f2bits(acc[mm][nt][3]);
                *(ushort4*)&vws[((size_t)bidx * 64 + j) * TT + t0] = pk;
            }
        }
    }
}

// ---------------- Kernel 2: flash attention, LDS-shared K/V (unchanged) --
__launch_bounds__(256, 3)
__global__ void flash_kernel(const ushort* __restrict__ qg, const ushort* __restrict__ kg,
                             const ushort* __restrict__ vtg, float* __restrict__ out,
                             float* __restrict__ pO, float* __restrict__ pM,
                             float* __restrict__ pL) {
    __shared__ ushort Ks[3][64 * 64];
    __shared__ ushort Vs[3][64 * 64];

    int tid  = threadIdx.x;
    int wid  = tid >> 6;
    int lane = tid & 63;
    int l31  = lane & 31;
    int hi   = lane >> 5;

    int b  = blockIdx.x / NTPB;
    int tp = blockIdx.x - b * NTPB;
    int g  = 0;
    while (tp >= ((g + 2) * (g + 2)) >> 2) g++;
    int seg   = tp - (((g + 1) * (g + 1)) >> 2);
    int nseg  = (g + 2) >> 1;
    int Qb    = g * 128;
    int Q0w   = Qb + wid * 32;
    int s_beg = seg * 256;
    int s_end = (s_beg + 256 < Qb + 128) ? s_beg + 256 : Qb + 128;
    int nt    = (s_end - s_beg) >> 6;

    int rS  = tid >> 3;
    int gcS = (tid & 7) ^ (rS & 7);
    const ushort* kS = kg  + ((size_t)b * TT + rS) * 64 + gcS * 8;
    const ushort* vS = vtg + ((size_t)b * 64 + rS) * TT + gcS * 8;

    auto stage = [&](int tt) {
        int buf = tt % 3;
        int ss  = s_beg + tt * 64;
        const ushort* kA = kS + (size_t)ss * 64;
        const ushort* vA = vS + ss;
        GLL16(kA,            &Ks[buf][tid * 8]);
        GLL16(kA + 32 * 64,  &Ks[buf][(tid + 256) * 8]);
        GLL16(vA,            &Vs[buf][tid * 8]);
        GLL16(vA + 32 * TT,  &Vs[buf][(tid + 256) * 8]);
    };

    const ushort* qp = qg + ((size_t)b * TT + Q0w + l31) * 64 + hi * 8;
    bf16x8 qf[4];
#pragma unroll
    for (int c = 0; c < 4; c++)
        qf[c] = __builtin_bit_cast(bf16x8, *(const uint4*)(qp + c * 16));

    f32x16 o0 = (f32x16)(0.f), o1 = (f32x16)(0.f);
    float m  = -INFINITY;
    float lp = 0.f;

    stage(0);
    if (nt > 1) stage(1);

    for (int t = 0; t < nt; t++) {
        if (t < nt - 1) asm volatile("s_waitcnt vmcnt(4)" ::: "memory");
        else            asm volatile("s_waitcnt vmcnt(0)" ::: "memory");
        __builtin_amdgcn_s_barrier();
        __builtin_amdgcn_sched_barrier(0);
        if (t + 2 < nt) stage(t + 2);

        int s0 = s_beg + t * 64;
        if (s0 < Q0w + 32) {
            int buf = t % 3;
            bf16x8 kf[2][4];
#pragma unroll
            for (int tt = 0; tt < 2; tt++) {
                int rk = tt * 32 + l31;
                const ushort* base = &Ks[buf][rk * 64];
                int sw = rk & 7;
#pragma unroll
                for (int c = 0; c < 4; c++)
                    kf[tt][c] = __builtin_bit_cast(bf16x8,
                        *(const uint4*)(base + (((c * 2 + hi) ^ sw) * 8)));
            }

            f32x16 st0 = (f32x16)(0.f), st1 = (f32x16)(0.f);
            __builtin_amdgcn_s_setprio(1);
#pragma unroll
            for (int c = 0; c < 4; c++)
                st0 = __builtin_amdgcn_mfma_f32_32x32x16_bf16(kf[0][c], qf[c], st0, 0, 0, 0);
#pragma unroll
            for (int c = 0; c < 4; c++)
                st1 = __builtin_amdgcn_mfma_f32_32x32x16_bf16(kf[1][c], qf[c], st1, 0, 0, 0);
            __builtin_amdgcn_s_setprio(0);

            if (s0 + 63 > Q0w) {
                int th0 = Q0w + l31 - s0 - 4 * hi;
                int th1 = th0 - 32;
#pragma unroll
                for (int r = 0; r < 16; r++) {
                    int kvl = (r & 3) + 8 * (r >> 2);
                    if (kvl > th0) st0[r] = -INFINITY;
                    if (kvl > th1) st1[r] = -INFINITY;
                }
            }

            float lmax = -INFINITY;
#pragma unroll
            for (int r = 0; r < 16; r++) lmax = fmaxf(lmax, fmaxf(st0[r], st1[r]));
            float pmax = fmaxf(lmax, __shfl_xor(lmax, 32));
            if (__any(pmax > m + 8.f)) {
                float mn = fmaxf(m, pmax);
                float al = __expf(m - mn);
                lp *= al;
#pragma unroll
                for (int r = 0; r < 16; r++) { o0[r] *= al; o1[r] *= al; }
                m = mn;
            }
#pragma unroll
            for (int r = 0; r < 16; r++) {
                st0[r] = __expf(st0[r] - m); lp += st0[r];
                st1[r] = __expf(st1[r] - m); lp += st1[r];
            }

            bf16x8 pf[4];
            {
                uint32_t w0, w1, w2, w3;
                w0 = cvtpk(st0[0], st0[1]);  w1 = cvtpk(st0[2], st0[3]);
                w2 = cvtpk(st0[4], st0[5]);  w3 = cvtpk(st0[6], st0[7]);
                pswap(w0, w2); pswap(w1, w3);
                uint4 u0 = {w0, w1, w2, w3}; pf[0] = __builtin_bit_cast(bf16x8, u0);
                w0 = cvtpk(st0[8], st0[9]);  w1 = cvtpk(st0[10], st0[11]);
                w2 = cvtpk(st0[12], st0[13]); w3 = cvtpk(st0[14], st0[15]);
                pswap(w0, w2); pswap(w1, w3);
                uint4 u1 = {w0, w1, w2, w3}; pf[1] = __builtin_bit_cast(bf16x8, u1);
                w0 = cvtpk(st1[0], st1[1]);  w1 = cvtpk(st1[2], st1[3]);
                w2 = cvtpk(st1[4], st1[5]);  w3 = cvtpk(st1[6], st1[7]);
                pswap(w0, w2); pswap(w1, w3);
                uint4 u2 = {w0, w1, w2, w3}; pf[2] = __builtin_bit_cast(bf16x8, u2);
                w0 = cvtpk(st1[8], st1[9]);  w1 = cvtpk(st1[10], st1[11]);
                w2 = cvtpk(st1[12], st1[13]); w3 = cvtpk(st1[14], st1[15]);
                pswap(w0, w2); pswap(w1, w3);
                uint4 u3 = {w0, w1, w2, w3}; pf[3] = __builtin_bit_cast(bf16x8, u3);
            }

            bf16x8 vf[2][4];
#pragma unroll
            for (int ht = 0; ht < 2; ht++) {
                int rv = ht * 32 + l31;
                const ushort* base = &Vs[buf][rv * 64];
                int sw = rv & 7;
#pragma unroll
                for (int c = 0; c < 4; c++)
                    vf[ht][c] = __builtin_bit_cast(bf16x8,
                        *(const uint4*)(base + (((c * 2 + hi) ^ sw) * 8)));
            }

            __builtin_amdgcn_s_setprio(1);
#pragma unroll
            for (int c = 0; c < 4; c++)
                o0 = __builtin_amdgcn_mfma_f32_32x32x16_bf16(vf[0][c], pf[c], o0, 0, 0, 0);
#pragma unroll
            for (int c = 0; c < 4; c++)
                o1 = __builtin_amdgcn_mfma_f32_32x32x16_bf16(vf[1][c], pf[c], o1, 0, 0, 0);
            __builtin_amdgcn_s_setprio(0);
        }
    }

    float lsum = lp + __shfl_xor(lp, 32);

    if (nseg == 1) {
        float inv = 1.f / lsum;
        float* ob = out + ((size_t)b * TT + Q0w + l31) * 64;
#pragma unroll
        for (int gg = 0; gg < 4; gg++) {
            float4 v0 = {o0[4*gg] * inv, o0[4*gg+1] * inv, o0[4*gg+2] * inv, o0[4*gg+3] * inv};
            *(float4*)(ob + 8 * gg + 4 * hi) = v0;
            float4 v1 = {o1[4*gg] * inv, o1[4*gg+1] * inv, o1[4*gg+2] * inv, o1[4*gg+3] * inv};
            *(float4*)(ob + 32 + 8 * gg + 4 * hi) = v1;
        }
    } else {
        int tb = b * NTPB + tp;
        float* pb = pO + (size_t)tb * 8192 + (size_t)(wid * 32 + l31) * 64;
#pragma unroll
        for (int gg = 0; gg < 4; gg++) {
            float4 v0 = {o0[4*gg], o0[4*gg+1], o0[4*gg+2], o0[4*gg+3]};
            *(float4*)(pb + 8 * gg + 4 * hi) = v0;
            float4 v1 = {o1[4*gg], o1[4*gg+1], o1[4*gg+2], o1[4*gg+3]};
            *(float4*)(pb + 32 + 8 * gg + 4 * hi) = v1;
        }
        if (hi == 0) {
            pM[(size_t)tb * 128 + wid * 32 + l31] = m;
            pL[(size_t)tb * 128 + wid * 32 + l31] = lsum;
        }
    }
}

// ---------------- Kernel 3: merge partials (g >= 2) ----------------------
__launch_bounds__(256)
__global__ void merge_kernel(const float* __restrict__ pO, const float* __restrict__ pM,
                             const float* __restrict__ pL, float* __restrict__ out) {
    int b    = blockIdx.x / 14;
    int g    = 2 + (blockIdx.x % 14);
    int nseg = (g + 2) >> 1;
    int tbase = b * NTPB + (((g + 1) * (g + 1)) >> 2);

    int row = threadIdx.x >> 1;
    int hh  = (threadIdx.x & 1) * 32;

    float mstar = -INFINITY;
    for (int s = 0; s < nseg; s++)
        mstar = fmaxf(mstar, pM[(size_t)(tbase + s) * 128 + row]);

    float oa[32];
#pragma unroll
    for (int i = 0; i < 32; i++) oa[i] = 0.f;
    float la = 0.f;
    for (int s = 0; s < nseg; s++) {
        float w = __expf(pM[(size_t)(tbase + s) * 128 + row] - mstar);
        la += w * pL[(size_t)(tbase + s) * 128 + row];
        const float* pp = pO + (size_t)(tbase + s) * 8192 + (size_t)row * 64 + hh;
#pragma unroll
        for (int i = 0; i < 8; i++) {
            float4 v = *(const float4*)(pp + i * 4);
            oa[i*4]   += w * v.x; oa[i*4+1] += w * v.y;
            oa[i*4+2] += w * v.z; oa[i*4+3] += w * v.w;
        }
    }
    float inv = 1.f / la;
    float* ob = out + ((size_t)b * TT + g * 128 + row) * 64 + hh;
#pragma unroll
    for (int i = 0; i < 8; i++) {
        float4 v = {oa[i*4] * inv, oa[i*4+1] * inv, oa[i*4+2] * inv, oa[i*4+3] * inv};
        *(float4*)(ob + i * 4) = v;
    }
}

// ---------------- launch --------------------------------------------------
extern "C" void kernel_launch(void* const* d_in, const int* in_sizes, int n_in,
                              void* d_out, int out_size, void* d_ws, size_t ws_size,
                              hipStream_t stream) {
    const float* x  = (const float*)d_in[0];
    const float* Wk = (const float*)d_in[1];
    const float* Wq = (const float*)d_in[2];
    const float* Wv = (const float*)d_in[3];
    float* out = (float*)d_out;

    char* ws = (char*)d_ws;
    ushort* WtF = (ushort*)(ws);                 // 288 KB (fragment-major)
    ushort* qws = (ushort*)(ws + 0x50000);       // 2 MB
    ushort* kws = (ushort*)(ws + 0x250000);      // 2 MB
    ushort* vws = (ushort*)(ws + 0x450000);      // 2 MB  [b][h][t]
    float*  pO  = (float*)(ws + 0x650000);       // 18.9 MB
    float*  pM  = (float*)(ws + 0x1850000);      // 288 KB
    float*  pL  = (float*)(ws + 0x1898000);      // 288 KB

    wt_kernel<<<36, 256, 0, stream>>>(Wk, Wq, Wv, WtF);
    qkv_kernel<<<(BB * TT) / 32, 256, 0, stream>>>(x, WtF, qws, kws, vws);
    flash_kernel<<<BB * NTPB, 256, 0, stream>>>(qws, kws, vws, out, pO, pM, pL);
    merge_kernel<<<BB * 14, 256, 0, stream>>>(pO, pM, pL, out);
}

// Round 10
// 55.010 us; speedup vs baseline: 1.7620x; 1.0408x over previous
//
#include <hip/hip_runtime.h>
#include <hip/hip_bf16.h>
#include <stdint.h>

#define BB 8
#define TT 2048
#define CC 768
#define NTPB 72   // flash block-tasks per batch: sum_{g=0..15} ceil((g+1)/2)

typedef __bf16 bf16x8 __attribute__((ext_vector_type(8)));
typedef float f32x4 __attribute__((ext_vector_type(4)));
typedef float f32x16 __attribute__((ext_vector_type(16)));

__device__ inline __bf16 f2b(float f) {
    __hip_bfloat16 h = __float2bfloat16(f);
    return __builtin_bit_cast(__bf16, h);
}
__device__ inline ushort f2bits(float f) {
    __hip_bfloat16 h = __float2bfloat16(f);
    return __builtin_bit_cast(ushort, h);
}
__device__ inline uint32_t cvtpk(float lo, float hi) {
    uint32_t r;
    asm("v_cvt_pk_bf16_f32 %0, %1, %2" : "=v"(r) : "v"(lo), "v"(hi));
    return r;
}
__device__ inline void pswap(uint32_t& a, uint32_t& b) {
    asm volatile("v_permlane32_swap_b32 %0, %1" : "+v"(a), "+v"(b));
}

#define GLL16(gp, lp)                                                          \
    __builtin_amdgcn_global_load_lds(                                          \
        (const __attribute__((address_space(1))) unsigned int*)(gp),           \
        (__attribute__((address_space(3))) unsigned int*)(lp), 16, 0, 0)

// ---------------- Kernel 0: W -> fragment-major bf16 WtF -----------------
// WtF element (c, k), c = m*64+j in [0,192), k in [0,768):
//   flat = ((k>>5)*192 + c)*32 + ((k>>3)&3)*8 + (k&7)
__launch_bounds__(256)
__global__ void wt_kernel(const float* __restrict__ Wk, const float* __restrict__ Wq,
                          const float* __restrict__ Wv, ushort* __restrict__ WtF) {
    __shared__ float tile[64][65];
    int m  = blockIdx.x / 12;
    int c0 = (blockIdx.x % 12) * 64;     // k-range base
    const float* W = (m == 0) ? Wq : ((m == 1) ? Wk : Wv);
    int tid = threadIdx.x;
#pragma unroll
    for (int i = 0; i < 4; i++) {
        int r   = (tid >> 4) + i * 16;
        int col = (tid & 15) * 4;
        float4 v = *(const float4*)&W[(size_t)(c0 + r) * 64 + col];
        tile[r][col] = v.x; tile[r][col + 1] = v.y;
        tile[r][col + 2] = v.z; tile[r][col + 3] = v.w;
    }
    __syncthreads();
    int j  = tid >> 2;            // col within 64
    int cc = (tid & 3) * 16;      // k offset within this 64-k block
    ushort tmp[16];
#pragma unroll
    for (int e = 0; e < 16; e++) tmp[e] = f2bits(tile[cc + e][j]);
    int c  = m * 64 + j;
    int kb = c0 + cc;             // multiple of 16
    int kc = kb >> 5;
    int h4 = (kb >> 3) & 3;       // 0 or 2
    ushort* dst = &WtF[((size_t)kc * 192 + c) * 32 + h4 * 8];
    *(uint4*)(dst)     = *(uint4*)&tmp[0];
    *(uint4*)(dst + 8) = *(uint4*)&tmp[8];
}

// ---------------- Kernel 1: QKV GEMM, all-gll BK=32 pipeline -------------
// Block: 32 rows x 192 cols, 4 waves. 24 K-steps, 4-deep LDS buffers; per
// step stage A-tile (4KB f32, 1 gll/thread) + B-tile (12KB WtF kc-slice,
// 3 gll/thread). ONLY gll ops in the loop -> clean counted vmcnt(12).
// B source pre-swizzled with involution P = L ^ ((L>>3)&3); A with
// chunk ^ (row&7). q pre-scaled by 0.125.
__launch_bounds__(256, 2)
__global__ void qkv_kernel(const float* __restrict__ x, const ushort* __restrict__ WtF,
                           ushort* __restrict__ qws, ushort* __restrict__ kws,
                           ushort* __restrict__ vws) {
    __shared__ float  xsA[4][32 * 32];   // 4 x 4 KB
    __shared__ ushort xsB[4][6144];      // 4 x 12 KB

    int tid  = threadIdx.x;
    int wid  = tid >> 6;
    int lane = tid & 63;
    int l15  = lane & 15;
    int hi4  = lane >> 4;
    int row0 = blockIdx.x * 32;

    // A staging: physical chunk = tid (row = tid>>3, cc = tid&7),
    // source chunk gc = cc ^ (row&7)
    int rA  = tid >> 3;
    int gcA = (tid & 7) ^ (rA & 7);
    const float* gpA = x + (size_t)(row0 + rA) * CC + gcA * 4;

    // B staging: physical chunks tid, tid+256, tid+512; L = P ^ ((P>>3)&3)
    int PB0 = tid, PB1 = tid + 256, PB2 = tid + 512;
    int LB0 = PB0 ^ ((PB0 >> 3) & 3);
    int LB1 = PB1 ^ ((PB1 >> 3) & 3);
    int LB2 = PB2 ^ ((PB2 >> 3) & 3);

    // B read: physical chunk per nt (kc-independent)
    int PrB[3];
#pragma unroll
    for (int nt = 0; nt < 3; nt++) {
        int Lr = (wid * 48 + nt * 16 + l15) * 4 + hi4;
        PrB[nt] = Lr ^ ((Lr >> 3) & 3);
    }

    f32x4 acc[2][3];
#pragma unroll
    for (int mm = 0; mm < 2; mm++)
#pragma unroll
        for (int nt = 0; nt < 3; nt++) acc[mm][nt] = (f32x4){0.f, 0.f, 0.f, 0.f};

    auto stage = [&](int t) {
        int buf = t & 3;
        GLL16(gpA + t * 32, &xsA[buf][(size_t)tid * 4]);
        const ushort* bsrc = WtF + (size_t)t * 6144;
        GLL16(bsrc + LB0 * 8, &xsB[buf][PB0 * 8]);
        GLL16(bsrc + LB1 * 8, &xsB[buf][PB1 * 8]);
        GLL16(bsrc + LB2 * 8, &xsB[buf][PB2 * 8]);
    };

    stage(0); stage(1); stage(2); stage(3);   // 16 gll in flight

#pragma unroll
    for (int t = 0; t < 24; t++) {
        if (t <= 20)      asm volatile("s_waitcnt vmcnt(12)" ::: "memory");
        else if (t == 21) asm volatile("s_waitcnt vmcnt(8)" ::: "memory");
        else if (t == 22) asm volatile("s_waitcnt vmcnt(4)" ::: "memory");
        else              asm volatile("s_waitcnt vmcnt(0)" ::: "memory");
        __builtin_amdgcn_s_barrier();
        __builtin_amdgcn_sched_barrier(0);

        int buf = t & 3;
        bf16x8 af[2];
#pragma unroll
        for (int mm = 0; mm < 2; mm++) {
            int row = mm * 16 + l15;
            const float* base = &xsA[buf][row * 32];
            float4 fa = *(const float4*)(base + (((2 * hi4)     ^ (row & 7)) * 4));
            float4 fb = *(const float4*)(base + (((2 * hi4 + 1) ^ (row & 7)) * 4));
            uint32_t w0 = cvtpk(fa.x, fa.y), w1 = cvtpk(fa.z, fa.w);
            uint32_t w2 = cvtpk(fb.x, fb.y), w3 = cvtpk(fb.z, fb.w);
            uint4 u = {w0, w1, w2, w3};
            af[mm] = __builtin_bit_cast(bf16x8, u);
        }
#pragma unroll
        for (int nt = 0; nt < 3; nt++) {
            bf16x8 b = __builtin_bit_cast(bf16x8, *(const uint4*)&xsB[buf][PrB[nt] * 8]);
            acc[0][nt] = __builtin_amdgcn_mfma_f32_16x16x32_bf16(af[0], b, acc[0][nt], 0, 0, 0);
            acc[1][nt] = __builtin_amdgcn_mfma_f32_16x16x32_bf16(af[1], b, acc[1][nt], 0, 0, 0);
        }
        __builtin_amdgcn_s_barrier();      // reads of buf done before refill
        if (t + 4 < 24) stage(t + 4);      // loads cross barriers
    }

    int bidx = row0 >> 11;
#pragma unroll
    for (int mm = 0; mm < 2; mm++) {
        int r0 = row0 + mm * 16 + 4 * hi4;
        int t0 = r0 & 2047;
#pragma unroll
        for (int nt = 0; nt < 3; nt++) {
            int c = wid * 48 + nt * 16 + l15;
            int m = c >> 6;
            int j = c & 63;
            if (m == 0) {
#pragma unroll
                for (int r = 0; r < 4; r++)
                    qws[(size_t)(r0 + r) * 64 + j] = f2bits(acc[mm][nt][r] * 0.125f);
            } else if (m == 1) {
#pragma unroll
                for (int r = 0; r < 4; r++)
                    kws[(size_t)(r0 + r) * 64 + j] = f2bits(acc[mm][nt][r]);
            } else {
                ushort4 pk;
                pk.x = f2bits(acc[mm][nt][0]);
                pk.y = f2bits(acc[mm][nt][1]);
                pk.z = f2bits(acc[mm][nt][2]);
                pk.w = f2bits(acc[mm][nt][3]);
                *(ushort4*)&vws[((size_t)bidx * 64 + j) * TT + t0] = pk;
            }
        }
    }
}

// ---------------- Kernel 2: flash attention, LDS-shared K/V (unchanged) --
__launch_bounds__(256, 3)
__global__ void flash_kernel(const ushort* __restrict__ qg, const ushort* __restrict__ kg,
                             const ushort* __restrict__ vtg, float* __restrict__ out,
                             float* __restrict__ pO, float* __restrict__ pM,
                             float* __restrict__ pL) {
    __shared__ ushort Ks[3][64 * 64];
    __shared__ ushort Vs[3][64 * 64];

    int tid  = threadIdx.x;
    int wid  = tid >> 6;
    int lane = tid & 63;
    int l31  = lane & 31;
    int hi   = lane >> 5;

    int b  = blockIdx.x / NTPB;
    int tp = blockIdx.x - b * NTPB;
    int g  = 0;
    while (tp >= ((g + 2) * (g + 2)) >> 2) g++;
    int seg   = tp - (((g + 1) * (g + 1)) >> 2);
    int nseg  = (g + 2) >> 1;
    int Qb    = g * 128;
    int Q0w   = Qb + wid * 32;
    int s_beg = seg * 256;
    int s_end = (s_beg + 256 < Qb + 128) ? s_beg + 256 : Qb + 128;
    int nt    = (s_end - s_beg) >> 6;

    int rS  = tid >> 3;
    int gcS = (tid & 7) ^ (rS & 7);
    const ushort* kS = kg  + ((size_t)b * TT + rS) * 64 + gcS * 8;
    const ushort* vS = vtg + ((size_t)b * 64 + rS) * TT + gcS * 8;

    auto stage = [&](int tt) {
        int buf = tt % 3;
        int ss  = s_beg + tt * 64;
        const ushort* kA = kS + (size_t)ss * 64;
        const ushort* vA = vS + ss;
        GLL16(kA,            &Ks[buf][tid * 8]);
        GLL16(kA + 32 * 64,  &Ks[buf][(tid + 256) * 8]);
        GLL16(vA,            &Vs[buf][tid * 8]);
        GLL16(vA + 32 * TT,  &Vs[buf][(tid + 256) * 8]);
    };

    const ushort* qp = qg + ((size_t)b * TT + Q0w + l31) * 64 + hi * 8;
    bf16x8 qf[4];
#pragma unroll
    for (int c = 0; c < 4; c++)
        qf[c] = __builtin_bit_cast(bf16x8, *(const uint4*)(qp + c * 16));

    f32x16 o0 = (f32x16)(0.f), o1 = (f32x16)(0.f);
    float m  = -INFINITY;
    float lp = 0.f;

    stage(0);
    if (nt > 1) stage(1);

    for (int t = 0; t < nt; t++) {
        if (t < nt - 1) asm volatile("s_waitcnt vmcnt(4)" ::: "memory");
        else            asm volatile("s_waitcnt vmcnt(0)" ::: "memory");
        __builtin_amdgcn_s_barrier();
        __builtin_amdgcn_sched_barrier(0);
        if (t + 2 < nt) stage(t + 2);

        int s0 = s_beg + t * 64;
        if (s0 < Q0w + 32) {
            int buf = t % 3;
            bf16x8 kf[2][4];
#pragma unroll
            for (int tt = 0; tt < 2; tt++) {
                int rk = tt * 32 + l31;
                const ushort* base = &Ks[buf][rk * 64];
                int sw = rk & 7;
#pragma unroll
                for (int c = 0; c < 4; c++)
                    kf[tt][c] = __builtin_bit_cast(bf16x8,
                        *(const uint4*)(base + (((c * 2 + hi) ^ sw) * 8)));
            }

            f32x16 st0 = (f32x16)(0.f), st1 = (f32x16)(0.f);
            __builtin_amdgcn_s_setprio(1);
#pragma unroll
            for (int c = 0; c < 4; c++)
                st0 = __builtin_amdgcn_mfma_f32_32x32x16_bf16(kf[0][c], qf[c], st0, 0, 0, 0);
#pragma unroll
            for (int c = 0; c < 4; c++)
                st1 = __builtin_amdgcn_mfma_f32_32x32x16_bf16(kf[1][c], qf[c], st1, 0, 0, 0);
            __builtin_amdgcn_s_setprio(0);

            if (s0 + 63 > Q0w) {
                int th0 = Q0w + l31 - s0 - 4 * hi;
                int th1 = th0 - 32;
#pragma unroll
                for (int r = 0; r < 16; r++) {
                    int kvl = (r & 3) + 8 * (r >> 2);
                    if (kvl > th0) st0[r] = -INFINITY;
                    if (kvl > th1) st1[r] = -INFINITY;
                }
            }

            float lmax = -INFINITY;
#pragma unroll
            for (int r = 0; r < 16; r++) lmax = fmaxf(lmax, fmaxf(st0[r], st1[r]));
            float pmax = fmaxf(lmax, __shfl_xor(lmax, 32));
            if (__any(pmax > m + 8.f)) {
                float mn = fmaxf(m, pmax);
                float al = __expf(m - mn);
                lp *= al;
#pragma unroll
                for (int r = 0; r < 16; r++) { o0[r] *= al; o1[r] *= al; }
                m = mn;
            }
#pragma unroll
            for (int r = 0; r < 16; r++) {
                st0[r] = __expf(st0[r] - m); lp += st0[r];
                st1[r] = __expf(st1[r] - m); lp += st1[r];
            }

            bf16x8 pf[4];
            {
                uint32_t w0, w1, w2, w3;
                w0 = cvtpk(st0[0], st0[1]);  w1 = cvtpk(st0[2], st0[3]);
                w2 = cvtpk(st0[4], st0[5]);  w3 = cvtpk(st0[6], st0[7]);
                pswap(w0, w2); pswap(w1, w3);
                uint4 u0 = {w0, w1, w2, w3}; pf[0] = __builtin_bit_cast(bf16x8, u0);
                w0 = cvtpk(st0[8], st0[9]);  w1 = cvtpk(st0[10], st0[11]);
                w2 = cvtpk(st0[12], st0[13]); w3 = cvtpk(st0[14], st0[15]);
                pswap(w0, w2); pswap(w1, w3);
                uint4 u1 = {w0, w1, w2, w3}; pf[1] = __builtin_bit_cast(bf16x8, u1);
                w0 = cvtpk(st1[0], st1[1]);  w1 = cvtpk(st1[2], st1[3]);
                w2 = cvtpk(st1[4], st1[5]);  w3 = cvtpk(st1[6], st1[7]);
                pswap(w0, w2); pswap(w1, w3);
                uint4 u2 = {w0, w1, w2, w3}; pf[2] = __builtin_bit_cast(bf16x8, u2);
                w0 = cvtpk(st1[8], st1[9]);  w1 = cvtpk(st1[10], st1[11]);
                w2 = cvtpk(st1[12], st1[13]); w3 = cvtpk(st1[14], st1[15]);
                pswap(w0, w2); pswap(w1, w3);
                uint4 u3 = {w0, w1, w2, w3}; pf[3] = __builtin_bit_cast(bf16x8, u3);
            }

            bf16x8 vf[2][4];
#pragma unroll
            for (int ht = 0; ht < 2; ht++) {
                int rv = ht * 32 + l31;
                const ushort* base = &Vs[buf][rv * 64];
                int sw = rv & 7;
#pragma unroll
                for (int c = 0; c < 4; c++)
                    vf[ht][c] = __builtin_bit_cast(bf16x8,
                        *(const uint4*)(base + (((c * 2 + hi) ^ sw) * 8)));
            }

            __builtin_amdgcn_s_setprio(1);
#pragma unroll
            for (int c = 0; c < 4; c++)
                o0 = __builtin_amdgcn_mfma_f32_32x32x16_bf16(vf[0][c], pf[c], o0, 0, 0, 0);
#pragma unroll
            for (int c = 0; c < 4; c++)
                o1 = __builtin_amdgcn_mfma_f32_32x32x16_bf16(vf[1][c], pf[c], o1, 0, 0, 0);
            __builtin_amdgcn_s_setprio(0);
        }
    }

    float lsum = lp + __shfl_xor(lp, 32);

    if (nseg == 1) {
        float inv = 1.f / lsum;
        float* ob = out + ((size_t)b * TT + Q0w + l31) * 64;
#pragma unroll
        for (int gg = 0; gg < 4; gg++) {
            float4 v0 = {o0[4*gg] * inv, o0[4*gg+1] * inv, o0[4*gg+2] * inv, o0[4*gg+3] * inv};
            *(float4*)(ob + 8 * gg + 4 * hi) = v0;
            float4 v1 = {o1[4*gg] * inv, o1[4*gg+1] * inv, o1[4*gg+2] * inv, o1[4*gg+3] * inv};
            *(float4*)(ob + 32 + 8 * gg + 4 * hi) = v1;
        }
    } else {
        int tb = b * NTPB + tp;
        float* pb = pO + (size_t)tb * 8192 + (size_t)(wid * 32 + l31) * 64;
#pragma unroll
        for (int gg = 0; gg < 4; gg++) {
            float4 v0 = {o0[4*gg], o0[4*gg+1], o0[4*gg+2], o0[4*gg+3]};
            *(float4*)(pb + 8 * gg + 4 * hi) = v0;
            float4 v1 = {o1[4*gg], o1[4*gg+1], o1[4*gg+2], o1[4*gg+3]};
            *(float4*)(pb + 32 + 8 * gg + 4 * hi) = v1;
        }
        if (hi == 0) {
            pM[(size_t)tb * 128 + wid * 32 + l31] = m;
            pL[(size_t)tb * 128 + wid * 32 + l31] = lsum;
        }
    }
}

// ---------------- Kernel 3: merge partials (g >= 2) ----------------------
__launch_bounds__(256)
__global__ void merge_kernel(const float* __restrict__ pO, const float* __restrict__ pM,
                             const float* __restrict__ pL, float* __restrict__ out) {
    int b    = blockIdx.x / 14;
    int g    = 2 + (blockIdx.x % 14);
    int nseg = (g + 2) >> 1;
    int tbase = b * NTPB + (((g + 1) * (g + 1)) >> 2);

    int row = threadIdx.x >> 1;
    int hh  = (threadIdx.x & 1) * 32;

    float mstar = -INFINITY;
    for (int s = 0; s < nseg; s++)
        mstar = fmaxf(mstar, pM[(size_t)(tbase + s) * 128 + row]);

    float oa[32];
#pragma unroll
    for (int i = 0; i < 32; i++) oa[i] = 0.f;
    float la = 0.f;
    for (int s = 0; s < nseg; s++) {
        float w = __expf(pM[(size_t)(tbase + s) * 128 + row] - mstar);
        la += w * pL[(size_t)(tbase + s) * 128 + row];
        const float* pp = pO + (size_t)(tbase + s) * 8192 + (size_t)row * 64 + hh;
#pragma unroll
        for (int i = 0; i < 8; i++) {
            float4 v = *(const float4*)(pp + i * 4);
            oa[i*4]   += w * v.x; oa[i*4+1] += w * v.y;
            oa[i*4+2] += w * v.z; oa[i*4+3] += w * v.w;
        }
    }
    float inv = 1.f / la;
    float* ob = out + ((size_t)b * TT + g * 128 + row) * 64 + hh;
#pragma unroll
    for (int i = 0; i < 8; i++) {
        float4 v = {oa[i*4] * inv, oa[i*4+1] * inv, oa[i*4+2] * inv, oa[i*4+3] * inv};
        *(float4*)(ob + i * 4) = v;
    }
}

// ---------------- launch --------------------------------------------------
extern "C" void kernel_launch(void* const* d_in, const int* in_sizes, int n_in,
                              void* d_out, int out_size, void* d_ws, size_t ws_size,
                              hipStream_t stream) {
    const float* x  = (const float*)d_in[0];
    const float* Wk = (const float*)d_in[1];
    const float* Wq = (const float*)d_in[2];
    const float* Wv = (const float*)d_in[3];
    float* out = (float*)d_out;

    char* ws = (char*)d_ws;
    ushort* WtF = (ushort*)(ws);                 // 288 KB (fragment-major)
    ushort* qws = (ushort*)(ws + 0x50000);       // 2 MB
    ushort* kws = (ushort*)(ws + 0x250000);      // 2 MB
    ushort* vws = (ushort*)(ws + 0x450000);      // 2 MB  [b][h][t]
    float*  pO  = (float*)(ws + 0x650000);       // 18.9 MB
    float*  pM  = (float*)(ws + 0x1850000);      // 288 KB
    float*  pL  = (float*)(ws + 0x1898000);      // 288 KB

    wt_kernel<<<36, 256, 0, stream>>>(Wk, Wq, Wv, WtF);
    qkv_kernel<<<(BB * TT) / 32, 256, 0, stream>>>(x, WtF, qws, kws, vws);
    flash_kernel<<<BB * NTPB, 256, 0, stream>>>(qws, kws, vws, out, pO, pM, pL);
    merge_kernel<<<BB * 14, 256, 0, stream>>>(pO, pM, pL, out);
}